// Round 1
// baseline (2090.201 us; speedup 1.0000x reference)
//
#include <hip/hip_runtime.h>

#define IN_DIM 256
#define HID 128

// ---------- monotone float<->uint encoding for atomicMax on floats ----------
__device__ __forceinline__ unsigned enc_f(float f) {
    unsigned u = __float_as_uint(f);
    return (u & 0x80000000u) ? ~u : (u | 0x80000000u);
}
__device__ __forceinline__ float dec_f(unsigned u) {
    return (u & 0x80000000u) ? __uint_as_float(u & 0x7FFFFFFFu) : __uint_as_float(~u);
}

// ---------- fp32 tiled GEMM: C[N,128] = A[N,K] @ W[K,128] (+bias) ----------
// BM=64, BN=128, BK=32, 256 threads. A-tile stored transposed in LDS so the
// inner loop reads it as a wave-broadcast float4.
template <int K>
__global__ __launch_bounds__(256) void gemm_nk(const float* __restrict__ A,
                                               const float* __restrict__ W,
                                               const float* __restrict__ bias,
                                               float* __restrict__ C, int N) {
    __shared__ float As[32][68];   // [kk][row], stride 68 floats (272B, 16B-aligned)
    __shared__ float Ws[32][128];
    const int tid = threadIdx.x;
    const int block_row = blockIdx.x * 64;
    const int tx = tid & 31;        // col group: cols tx*4..tx*4+3
    const int ty = tid >> 5;        // row group: rows ty*8..ty*8+7

    float acc[8][4];
#pragma unroll
    for (int i = 0; i < 8; ++i)
#pragma unroll
        for (int j = 0; j < 4; ++j) acc[i][j] = 0.f;

    const int lc = tid & 7;   // A-load: K-subcol group
    const int lr = tid >> 3;  // A-load: row 0..31 (and +32)

    for (int k0 = 0; k0 < K; k0 += 32) {
        // load A tile (64x32), transposed into As[kk][row]
#pragma unroll
        for (int rr = lr; rr < 64; rr += 32) {
            const int grow = block_row + rr;
            float4 v = make_float4(0.f, 0.f, 0.f, 0.f);
            if (grow < N)
                v = *reinterpret_cast<const float4*>(A + (size_t)grow * K + k0 + lc * 4);
            As[lc * 4 + 0][rr] = v.x;
            As[lc * 4 + 1][rr] = v.y;
            As[lc * 4 + 2][rr] = v.z;
            As[lc * 4 + 3][rr] = v.w;
        }
        // load W tile (32x128)
#pragma unroll
        for (int kk = ty; kk < 32; kk += 8) {
            *reinterpret_cast<float4*>(&Ws[kk][tx * 4]) =
                *reinterpret_cast<const float4*>(W + (size_t)(k0 + kk) * HID + tx * 4);
        }
        __syncthreads();
#pragma unroll
        for (int kk = 0; kk < 32; ++kk) {
            const float4 a0 = *reinterpret_cast<const float4*>(&As[kk][ty * 8]);
            const float4 a1 = *reinterpret_cast<const float4*>(&As[kk][ty * 8 + 4]);
            const float4 b = *reinterpret_cast<const float4*>(&Ws[kk][tx * 4]);
            const float av[8] = {a0.x, a0.y, a0.z, a0.w, a1.x, a1.y, a1.z, a1.w};
            const float bv[4] = {b.x, b.y, b.z, b.w};
#pragma unroll
            for (int i = 0; i < 8; ++i)
#pragma unroll
                for (int j = 0; j < 4; ++j) acc[i][j] += av[i] * bv[j];
        }
        __syncthreads();
    }

    float badd[4] = {0.f, 0.f, 0.f, 0.f};
    if (bias) {
        badd[0] = bias[tx * 4 + 0];
        badd[1] = bias[tx * 4 + 1];
        badd[2] = bias[tx * 4 + 2];
        badd[3] = bias[tx * 4 + 3];
    }
#pragma unroll
    for (int i = 0; i < 8; ++i) {
        const int grow = block_row + ty * 8 + i;
        if (grow < N) {
            float4 o;
            o.x = acc[i][0] + badd[0];
            o.y = acc[i][1] + badd[1];
            o.z = acc[i][2] + badd[2];
            o.w = acc[i][3] + badd[3];
            *reinterpret_cast<float4*>(C + (size_t)grow * HID + tx * 4) = o;
        }
    }
}

// ---------- out[row] = dot(X[row,:128], v[:128]) (wave per row) ----------
__global__ __launch_bounds__(256) void rowdot_k(const float* __restrict__ X,
                                                const float* __restrict__ v,
                                                float* __restrict__ out, int N) {
    const int idx = blockIdx.x * blockDim.x + threadIdx.x;
    const int row = idx >> 6;
    const int lane = threadIdx.x & 63;
    if (row >= N) return;
    const float* x = X + (size_t)row * HID;
    float p = x[lane] * v[lane] + x[lane + 64] * v[lane + 64];
#pragma unroll
    for (int off = 32; off > 0; off >>= 1) p += __shfl_xor(p, off, 64);
    if (lane == 0) out[row] = p;
}

// ---------- wd_all[lr][k] = dot(Wd[lr][k][:], ad[lr][:]) for lr in 0..9 ----------
__global__ __launch_bounds__(256) void wdvec_k(const float* __restrict__ Wd,
                                               const float* __restrict__ ad,
                                               float* __restrict__ wd_all) {
    const int idx = blockIdx.x * blockDim.x + threadIdx.x;
    const int row = idx >> 6;  // 0..1279
    const int lane = threadIdx.x & 63;
    if (row >= 10 * HID) return;
    const int lr = row >> 7;
    const float* w = Wd + (size_t)row * HID;
    const float* a = ad + (size_t)lr * HID;
    float p = w[lane] * a[lane] + w[lane + 64] * a[lane + 64];
#pragma unroll
    for (int off = 32; off > 0; off >>= 1) p += __shfl_xor(p, off, 64);
    if (lane == 0) wd_all[row] = p;
}

// ---------- final: out[row] = dot(X[row,:], w) + b[0] ----------
__global__ __launch_bounds__(256) void out_proj_k(const float* __restrict__ X,
                                                  const float* __restrict__ w,
                                                  const float* __restrict__ b,
                                                  float* __restrict__ out, int N) {
    const int idx = blockIdx.x * blockDim.x + threadIdx.x;
    const int row = idx >> 6;
    const int lane = threadIdx.x & 63;
    if (row >= N) return;
    const float* x = X + (size_t)row * HID;
    float p = x[lane] * w[lane] + x[lane + 64] * w[lane + 64];
#pragma unroll
    for (int off = 32; off > 0; off >>= 1) p += __shfl_xor(p, off, 64);
    if (lane == 0) out[row] = p + b[0];
}

// ---------- edge pass A: e = leaky_relu(as[src]+ad[dst]); atomicMax m ----------
__global__ __launch_bounds__(256) void edge_a_k(const int* __restrict__ src,
                                                const int* __restrict__ dst,
                                                const float* __restrict__ as_s,
                                                const float* __restrict__ ad_s,
                                                float* __restrict__ ebuf,
                                                unsigned* __restrict__ m_enc, int E) {
    const int e = blockIdx.x * blockDim.x + threadIdx.x;
    if (e >= E) return;
    const int s = src[e], d = dst[e];
    float v = as_s[s] + ad_s[d];
    v = v > 0.f ? v : 0.2f * v;
    ebuf[e] = v;
    atomicMax(m_enc + d, enc_f(v));
}

// ---------- edge pass B: ex = exp(e - m[dst]); atomicAdd denom ----------
__global__ __launch_bounds__(256) void edge_b_k(const int* __restrict__ dst,
                                                float* __restrict__ ebuf,
                                                const unsigned* __restrict__ m_enc,
                                                float* __restrict__ denom, int E) {
    const int e = blockIdx.x * blockDim.x + threadIdx.x;
    if (e >= E) return;
    const int d = dst[e];
    const float ex = expf(ebuf[e] - dec_f(m_enc[d]));
    ebuf[e] = ex;
    atomicAdd(denom + d, ex);
}

// ---------- edge pass C: out[dst] += alpha * hs[src] (wave per edge) ----------
__global__ __launch_bounds__(256) void edge_c_k(const int* __restrict__ src,
                                                const int* __restrict__ dst,
                                                const float* __restrict__ ebuf,
                                                const float* __restrict__ denom,
                                                const float* __restrict__ hs,
                                                float* __restrict__ out, int E) {
    const int idx = blockIdx.x * blockDim.x + threadIdx.x;
    const int e = idx >> 6;
    const int lane = threadIdx.x & 63;
    if (e >= E) return;
    const int s = src[e], d = dst[e];
    const float alpha = ebuf[e] / (denom[d] + 1e-16f);
    const float* hrow = hs + (size_t)s * HID;
    float* orow = out + (size_t)d * HID;
    atomicAdd(orow + lane, alpha * hrow[lane]);
    atomicAdd(orow + lane + 64, alpha * hrow[lane + 64]);
}

// ---------- acc init: acc[i] = b1[i%128] (+ b2[i%128]) ----------
__global__ __launch_bounds__(256) void init_acc_k(float* __restrict__ acc,
                                                  const float* __restrict__ b1,
                                                  const float* __restrict__ b2, int total) {
    const int i = blockIdx.x * blockDim.x + threadIdx.x;
    if (i >= total) return;
    const int c = i & (HID - 1);
    float v = b1[c];
    if (b2) v += b2[c];
    acc[i] = v;
}

__global__ __launch_bounds__(256) void relu_k(const float* __restrict__ a,
                                              float* __restrict__ x, int total) {
    const int i = blockIdx.x * blockDim.x + threadIdx.x;
    if (i < total) x[i] = fmaxf(a[i], 0.f);
}

static inline void launch_gemm(const float* A, const float* W, const float* bias, float* C,
                               int N, int K, hipStream_t s) {
    dim3 g((N + 63) / 64), b(256);
    if (K == 256)
        gemm_nk<256><<<g, b, 0, s>>>(A, W, bias, C, N);
    else
        gemm_nk<128><<<g, b, 0, s>>>(A, W, bias, C, N);
}

extern "C" void kernel_launch(void* const* d_in, const int* in_sizes, int n_in,
                              void* d_out, int out_size, void* d_ws, size_t ws_size,
                              hipStream_t stream) {
    const float* xin[4];
    for (int i = 0; i < 4; ++i) xin[i] = (const float*)d_in[i];
    const int* eptr[5];
    int Ecnt[5];
    for (int r = 0; r < 5; ++r) {
        eptr[r] = (const int*)d_in[4 + r];
        Ecnt[r] = in_sizes[4 + r] / 2;
    }
    const float* lin_W = (const float*)d_in[9];
    const float* lin_b = (const float*)d_in[10];
    const float* conv_Ws = (const float*)d_in[11];
    const float* conv_Wd = (const float*)d_in[12];
    const float* conv_as = (const float*)d_in[13];
    const float* conv_ad = (const float*)d_in[14];
    const float* conv_b = (const float*)d_in[15];
    const float* out_W = (const float*)d_in[16];
    const float* out_b = (const float*)d_in[17];

    int Nn[4];
    for (int i = 0; i < 4; ++i) Nn[i] = in_sizes[i] / IN_DIM;  // QENT, CENT, SPAN, SENT
    const int NQ = Nn[0], NC = Nn[1], NS = Nn[2], NT = Nn[3];
    (void)NQ; (void)n_in;

    int maxN = 0, maxE = 0;
    for (int i = 0; i < 4; ++i) maxN = Nn[i] > maxN ? Nn[i] : maxN;
    for (int r = 0; r < 5; ++r) maxE = Ecnt[r] > maxE ? Ecnt[r] : maxE;

    // ---- workspace carve (floats). Total ~171 MB. ----
    float* ws = (float*)d_ws;
    size_t off = 0;
    auto alloc = [&](size_t n) { float* p = ws + off; off += n; return p; };
    float* xq = alloc((size_t)Nn[0] * HID);
    float* xc = alloc((size_t)Nn[1] * HID);
    float* xs = alloc((size_t)Nn[2] * HID);
    float* xt = alloc((size_t)Nn[3] * HID);
    float* acc_span = alloc((size_t)NS * HID);
    float* acc_sent = alloc((size_t)NT * HID);
    float* acc_cent = alloc((size_t)NC * HID);
    float* hs = alloc((size_t)maxN * HID);
    float* as_s = alloc(maxN);
    float* ad_s = alloc(maxN);
    unsigned* m_enc = (unsigned*)alloc(maxN);
    float* denom = alloc(maxN);
    float* ebuf = alloc(maxE);
    float* wd_all = alloc(10 * HID);
    (void)ws_size;

    float* xbuf[4] = {xq, xc, xs, xt};

    // 1. per-type input projection: x[t] = xin[t] @ lin_W[t] + lin_b[t]
    for (int t = 0; t < 4; ++t)
        launch_gemm(xin[t], lin_W + (size_t)t * IN_DIM * HID, lin_b + (size_t)t * HID,
                    xbuf[t], Nn[t], IN_DIM, stream);

    // 2. wd vectors: wd_all[l*5+r] = conv_Wd[l,r] @ conv_ad[l,r]  (10 mat-vecs)
    wdvec_k<<<dim3((10 * HID * 64 + 255) / 256), dim3(256), 0, stream>>>(conv_Wd, conv_ad,
                                                                          wd_all);

    // relation table: src type, dst type, accumulator
    const int rsrc[5] = {0, 0, 1, 2, 1};
    const int rdst[5] = {2, 3, 3, 1, 1};
    float* racc[5] = {acc_span, acc_sent, acc_sent, acc_cent, acc_cent};

    for (int l = 0; l < 2; ++l) {
        const float* cb = conv_b + (size_t)l * 5 * HID;
        init_acc_k<<<dim3(((size_t)NS * HID + 255) / 256), dim3(256), 0, stream>>>(
            acc_span, cb + 0 * HID, nullptr, NS * HID);
        init_acc_k<<<dim3(((size_t)NT * HID + 255) / 256), dim3(256), 0, stream>>>(
            acc_sent, cb + 1 * HID, cb + 2 * HID, NT * HID);
        init_acc_k<<<dim3(((size_t)NC * HID + 255) / 256), dim3(256), 0, stream>>>(
            acc_cent, cb + 3 * HID, cb + 4 * HID, NC * HID);

        for (int r = 0; r < 5; ++r) {
            const int st = rsrc[r], dt = rdst[r];
            const int Nsrc = Nn[st], Ndst = Nn[dt];
            const int E = Ecnt[r];
            const int* srcp = eptr[r];
            const int* dstp = eptr[r] + E;
            const size_t lr = (size_t)l * 5 + r;

            launch_gemm(xbuf[st], conv_Ws + lr * HID * HID, nullptr, hs, Nsrc, HID, stream);
            rowdot_k<<<dim3(((size_t)Nsrc * 64 + 255) / 256), dim3(256), 0, stream>>>(
                hs, conv_as + lr * HID, as_s, Nsrc);
            rowdot_k<<<dim3(((size_t)Ndst * 64 + 255) / 256), dim3(256), 0, stream>>>(
                xbuf[dt], wd_all + lr * HID, ad_s, Ndst);

            hipMemsetAsync(m_enc, 0, (size_t)Ndst * 4, stream);
            hipMemsetAsync(denom, 0, (size_t)Ndst * 4, stream);

            edge_a_k<<<dim3((E + 255) / 256), dim3(256), 0, stream>>>(srcp, dstp, as_s, ad_s,
                                                                      ebuf, m_enc, E);
            edge_b_k<<<dim3((E + 255) / 256), dim3(256), 0, stream>>>(dstp, ebuf, m_enc,
                                                                      denom, E);
            edge_c_k<<<dim3(((size_t)E * 64 + 255) / 256), dim3(256), 0, stream>>>(
                srcp, dstp, ebuf, denom, hs, racc[r], E);
        }

        relu_k<<<dim3(((size_t)NS * HID + 255) / 256), dim3(256), 0, stream>>>(
            acc_span, xbuf[2], NS * HID);
        relu_k<<<dim3(((size_t)NT * HID + 255) / 256), dim3(256), 0, stream>>>(
            acc_sent, xbuf[3], NT * HID);
        relu_k<<<dim3(((size_t)NC * HID + 255) / 256), dim3(256), 0, stream>>>(
            acc_cent, xbuf[1], NC * HID);
    }

    // 3. output projection on SPAN
    out_proj_k<<<dim3(((size_t)NS * 64 + 255) / 256), dim3(256), 0, stream>>>(
        xbuf[2], out_W, out_b, (float*)d_out, NS);
}

// Round 2
// 1776.946 us; speedup vs baseline: 1.1763x; 1.1763x over previous
//
#include <hip/hip_runtime.h>

#define IN_DIM 256
#define HID 128

// ---------- fp32 tiled GEMM: C[N,128] = A[N,K] @ W[K,128] (+bias) ----------
template <int K>
__global__ __launch_bounds__(256) void gemm_nk(const float* __restrict__ A,
                                               const float* __restrict__ W,
                                               const float* __restrict__ bias,
                                               float* __restrict__ C, int N) {
    __shared__ float As[32][68];
    __shared__ float Ws[32][128];
    const int tid = threadIdx.x;
    const int block_row = blockIdx.x * 64;
    const int tx = tid & 31;
    const int ty = tid >> 5;

    float acc[8][4];
#pragma unroll
    for (int i = 0; i < 8; ++i)
#pragma unroll
        for (int j = 0; j < 4; ++j) acc[i][j] = 0.f;

    const int lc = tid & 7;
    const int lr = tid >> 3;

    for (int k0 = 0; k0 < K; k0 += 32) {
#pragma unroll
        for (int rr = lr; rr < 64; rr += 32) {
            const int grow = block_row + rr;
            float4 v = make_float4(0.f, 0.f, 0.f, 0.f);
            if (grow < N)
                v = *reinterpret_cast<const float4*>(A + (size_t)grow * K + k0 + lc * 4);
            As[lc * 4 + 0][rr] = v.x;
            As[lc * 4 + 1][rr] = v.y;
            As[lc * 4 + 2][rr] = v.z;
            As[lc * 4 + 3][rr] = v.w;
        }
#pragma unroll
        for (int kk = ty; kk < 32; kk += 8) {
            *reinterpret_cast<float4*>(&Ws[kk][tx * 4]) =
                *reinterpret_cast<const float4*>(W + (size_t)(k0 + kk) * HID + tx * 4);
        }
        __syncthreads();
#pragma unroll
        for (int kk = 0; kk < 32; ++kk) {
            const float4 a0 = *reinterpret_cast<const float4*>(&As[kk][ty * 8]);
            const float4 a1 = *reinterpret_cast<const float4*>(&As[kk][ty * 8 + 4]);
            const float4 b = *reinterpret_cast<const float4*>(&Ws[kk][tx * 4]);
            const float av[8] = {a0.x, a0.y, a0.z, a0.w, a1.x, a1.y, a1.z, a1.w};
            const float bv[4] = {b.x, b.y, b.z, b.w};
#pragma unroll
            for (int i = 0; i < 8; ++i)
#pragma unroll
                for (int j = 0; j < 4; ++j) acc[i][j] += av[i] * bv[j];
        }
        __syncthreads();
    }

    float badd[4] = {0.f, 0.f, 0.f, 0.f};
    if (bias) {
        badd[0] = bias[tx * 4 + 0];
        badd[1] = bias[tx * 4 + 1];
        badd[2] = bias[tx * 4 + 2];
        badd[3] = bias[tx * 4 + 3];
    }
#pragma unroll
    for (int i = 0; i < 8; ++i) {
        const int grow = block_row + ty * 8 + i;
        if (grow < N) {
            float4 o;
            o.x = acc[i][0] + badd[0];
            o.y = acc[i][1] + badd[1];
            o.z = acc[i][2] + badd[2];
            o.w = acc[i][3] + badd[3];
            *reinterpret_cast<float4*>(C + (size_t)grow * HID + tx * 4) = o;
        }
    }
}

// ---------- out[row] = dot(X[row,:128], v[:128]) (wave per row) ----------
__global__ __launch_bounds__(256) void rowdot_k(const float* __restrict__ X,
                                                const float* __restrict__ v,
                                                float* __restrict__ out, int N) {
    const int idx = blockIdx.x * blockDim.x + threadIdx.x;
    const int row = idx >> 6;
    const int lane = threadIdx.x & 63;
    if (row >= N) return;
    const float* x = X + (size_t)row * HID;
    float p = x[lane] * v[lane] + x[lane + 64] * v[lane + 64];
#pragma unroll
    for (int off = 32; off > 0; off >>= 1) p += __shfl_xor(p, off, 64);
    if (lane == 0) out[row] = p;
}

// ---------- wd_all[lr][k] = dot(Wd[lr][k][:], ad[lr][:]) ----------
__global__ __launch_bounds__(256) void wdvec_k(const float* __restrict__ Wd,
                                               const float* __restrict__ ad,
                                               float* __restrict__ wd_all) {
    const int idx = blockIdx.x * blockDim.x + threadIdx.x;
    const int row = idx >> 6;  // 0..1279
    const int lane = threadIdx.x & 63;
    if (row >= 10 * HID) return;
    const int lr = row >> 7;
    const float* w = Wd + (size_t)row * HID;
    const float* a = ad + (size_t)lr * HID;
    float p = w[lane] * a[lane] + w[lane + 64] * a[lane + 64];
#pragma unroll
    for (int off = 32; off > 0; off >>= 1) p += __shfl_xor(p, off, 64);
    if (lane == 0) wd_all[row] = p;
}

// ---------- final: out[row] = dot(X[row,:], w) + b[0] ----------
__global__ __launch_bounds__(256) void out_proj_k(const float* __restrict__ X,
                                                  const float* __restrict__ w,
                                                  const float* __restrict__ b,
                                                  float* __restrict__ out, int N) {
    const int idx = blockIdx.x * blockDim.x + threadIdx.x;
    const int row = idx >> 6;
    const int lane = threadIdx.x & 63;
    if (row >= N) return;
    const float* x = X + (size_t)row * HID;
    float p = x[lane] * w[lane] + x[lane + 64] * w[lane + 64];
#pragma unroll
    for (int off = 32; off > 0; off >>= 1) p += __shfl_xor(p, off, 64);
    if (lane == 0) out[row] = p + b[0];
}

// ================= CSR build (once per relation, reused both layers) =========
__global__ __launch_bounds__(256) void hist_k(const int* __restrict__ dst,
                                              int* __restrict__ deg, int E) {
    const int e = blockIdx.x * blockDim.x + threadIdx.x;
    if (e < E) atomicAdd(deg + dst[e], 1);
}

// single-block exclusive scan; deg and cursor may alias (each thread only
// touches its own chunk, all reads of other chunks happen via LDS sums)
__global__ __launch_bounds__(1024) void scan_k(const int* __restrict__ deg,
                                               int* __restrict__ row_ptr,
                                               int* __restrict__ cursor, int N) {
    __shared__ int sums[1024];
    const int t = threadIdx.x;
    const int chunk = (N + 1023) >> 10;
    const int b = t * chunk;
    const int e = min(b + chunk, N);
    int s = 0;
    for (int i = b; i < e; ++i) s += deg[i];
    sums[t] = s;
    __syncthreads();
    for (int off = 1; off < 1024; off <<= 1) {
        int v = (t >= off) ? sums[t - off] : 0;
        __syncthreads();
        sums[t] += v;
        __syncthreads();
    }
    int prefix = (t == 0) ? 0 : sums[t - 1];
    for (int i = b; i < e; ++i) {
        const int d = deg[i];
        row_ptr[i] = prefix;
        cursor[i] = prefix;
        prefix += d;
    }
    if (t == 1023) row_ptr[N] = prefix;
}

__global__ __launch_bounds__(256) void scatter_k(const int* __restrict__ src,
                                                 const int* __restrict__ dst,
                                                 int* __restrict__ cursor,
                                                 int* __restrict__ col, int E) {
    const int e = blockIdx.x * blockDim.x + threadIdx.x;
    if (e >= E) return;
    const int pos = atomicAdd(cursor + dst[e], 1);
    col[pos] = src[e];
}

// ========== fused per-dst GAT: softmax + weighted gather, 1 wave / dst =======
__global__ __launch_bounds__(256) void gat_dst_k(const int* __restrict__ row_ptr,
                                                 const int* __restrict__ col,
                                                 const float* __restrict__ as_s,
                                                 const float* __restrict__ ad_s,
                                                 const float* __restrict__ hs,
                                                 float* __restrict__ out, int Ndst) {
    const int idx = blockIdx.x * blockDim.x + threadIdx.x;
    const int row = idx >> 6;
    const int lane = threadIdx.x & 63;
    if (row >= Ndst) return;
    const int beg = row_ptr[row];
    const int end = row_ptr[row + 1];
    if (beg == end) return;  // no edges: out keeps its bias preinit
    const float ad = ad_s[row];

    // pass 1: segment max (lane-distributed)
    float m = -INFINITY;
    for (int e = beg + lane; e < end; e += 64) {
        float ev = as_s[col[e]] + ad;
        ev = ev > 0.f ? ev : 0.2f * ev;
        m = fmaxf(m, ev);
    }
#pragma unroll
    for (int off = 32; off > 0; off >>= 1) m = fmaxf(m, __shfl_xor(m, off, 64));

    // pass 2: denom (lane-distributed)
    float dsum = 0.f;
    for (int e = beg + lane; e < end; e += 64) {
        float ev = as_s[col[e]] + ad;
        ev = ev > 0.f ? ev : 0.2f * ev;
        dsum += expf(ev - m);
    }
#pragma unroll
    for (int off = 32; off > 0; off >>= 1) dsum += __shfl_xor(dsum, off, 64);
    const float inv = 1.f / (dsum + 1e-16f);

    // pass 3: serial over edges, wave-wide coalesced gather of hs rows
    float a0 = 0.f, a1 = 0.f;
    for (int e = beg; e < end; ++e) {
        const int s = col[e];  // same addr all lanes -> broadcast
        float ev = as_s[s] + ad;
        ev = ev > 0.f ? ev : 0.2f * ev;
        const float alpha = expf(ev - m) * inv;
        const float* h = hs + (size_t)s * HID;
        a0 += alpha * h[lane];
        a1 += alpha * h[lane + 64];
    }
    float* orow = out + (size_t)row * HID;
    orow[lane] += a0;
    orow[lane + 64] += a1;
}

// ---------- acc init: acc[i] = b1[i%128] (+ b2[i%128]) ----------
__global__ __launch_bounds__(256) void init_acc_k(float* __restrict__ acc,
                                                  const float* __restrict__ b1,
                                                  const float* __restrict__ b2, int total) {
    const int i = blockIdx.x * blockDim.x + threadIdx.x;
    if (i >= total) return;
    const int c = i & (HID - 1);
    float v = b1[c];
    if (b2) v += b2[c];
    acc[i] = v;
}

__global__ __launch_bounds__(256) void relu_k(const float* __restrict__ a,
                                              float* __restrict__ x, int total) {
    const int i = blockIdx.x * blockDim.x + threadIdx.x;
    if (i < total) x[i] = fmaxf(a[i], 0.f);
}

static inline void launch_gemm(const float* A, const float* W, const float* bias, float* C,
                               int N, int K, hipStream_t s) {
    dim3 g((N + 63) / 64), b(256);
    if (K == 256)
        gemm_nk<256><<<g, b, 0, s>>>(A, W, bias, C, N);
    else
        gemm_nk<128><<<g, b, 0, s>>>(A, W, bias, C, N);
}

extern "C" void kernel_launch(void* const* d_in, const int* in_sizes, int n_in,
                              void* d_out, int out_size, void* d_ws, size_t ws_size,
                              hipStream_t stream) {
    const float* xin[4];
    for (int i = 0; i < 4; ++i) xin[i] = (const float*)d_in[i];
    const int* eptr[5];
    int Ecnt[5];
    for (int r = 0; r < 5; ++r) {
        eptr[r] = (const int*)d_in[4 + r];
        Ecnt[r] = in_sizes[4 + r] / 2;
    }
    const float* lin_W = (const float*)d_in[9];
    const float* lin_b = (const float*)d_in[10];
    const float* conv_Ws = (const float*)d_in[11];
    const float* conv_Wd = (const float*)d_in[12];
    const float* conv_as = (const float*)d_in[13];
    const float* conv_ad = (const float*)d_in[14];
    const float* conv_b = (const float*)d_in[15];
    const float* out_W = (const float*)d_in[16];
    const float* out_b = (const float*)d_in[17];

    int Nn[4];
    for (int i = 0; i < 4; ++i) Nn[i] = in_sizes[i] / IN_DIM;  // QENT, CENT, SPAN, SENT
    const int NQ = Nn[0], NC = Nn[1], NS = Nn[2], NT = Nn[3];
    (void)NQ; (void)n_in; (void)out_size;

    int maxN = 0, maxE = 0;
    for (int i = 0; i < 4; ++i) maxN = Nn[i] > maxN ? Nn[i] : maxN;
    for (int r = 0; r < 5; ++r) maxE = Ecnt[r] > maxE ? Ecnt[r] : maxE;

    // relation table: src type, dst type
    const int rsrc[5] = {0, 0, 1, 2, 1};
    const int rdst[5] = {2, 3, 3, 1, 1};

    // ---- workspace carve ----
    float* ws = (float*)d_ws;
    size_t off = 0;
    auto alloc = [&](size_t n) { float* p = ws + off; off += n; return p; };
    float* xq = alloc((size_t)Nn[0] * HID);
    float* xc = alloc((size_t)Nn[1] * HID);
    float* xs = alloc((size_t)Nn[2] * HID);
    float* xt = alloc((size_t)Nn[3] * HID);
    float* acc_span = alloc((size_t)NS * HID);
    float* acc_sent = alloc((size_t)NT * HID);
    float* acc_cent = alloc((size_t)NC * HID);
    float* hs = alloc((size_t)maxN * HID);
    float* as_s = alloc(maxN);
    float* ad_s = alloc(maxN);
    float* wd_all = alloc(10 * HID);
    int* cursor = (int*)alloc(maxN);
    int* row_ptr[5];
    int* col[5];
    for (int r = 0; r < 5; ++r) {
        row_ptr[r] = (int*)alloc((size_t)Nn[rdst[r]] + 1);
        col[r] = (int*)alloc((size_t)Ecnt[r]);
    }
    (void)ws_size;

    float* xbuf[4] = {xq, xc, xs, xt};
    float* racc[5] = {acc_span, acc_sent, acc_sent, acc_cent, acc_cent};

    // 0. build dst-CSR once per relation (edges identical across layers)
    for (int r = 0; r < 5; ++r) {
        const int E = Ecnt[r];
        const int Ndst = Nn[rdst[r]];
        const int* srcp = eptr[r];
        const int* dstp = eptr[r] + E;
        hipMemsetAsync(cursor, 0, (size_t)Ndst * 4, stream);
        hist_k<<<dim3((E + 255) / 256), dim3(256), 0, stream>>>(dstp, cursor, E);
        scan_k<<<dim3(1), dim3(1024), 0, stream>>>(cursor, row_ptr[r], cursor, Ndst);
        scatter_k<<<dim3((E + 255) / 256), dim3(256), 0, stream>>>(srcp, dstp, cursor,
                                                                   col[r], E);
    }

    // 1. per-type input projection
    for (int t = 0; t < 4; ++t)
        launch_gemm(xin[t], lin_W + (size_t)t * IN_DIM * HID, lin_b + (size_t)t * HID,
                    xbuf[t], Nn[t], IN_DIM, stream);

    // 2. wd vectors: wd_all[l*5+r] = conv_Wd[l,r] @ conv_ad[l,r]
    wdvec_k<<<dim3((10 * HID * 64 + 255) / 256), dim3(256), 0, stream>>>(conv_Wd, conv_ad,
                                                                          wd_all);

    for (int l = 0; l < 2; ++l) {
        const float* cb = conv_b + (size_t)l * 5 * HID;
        init_acc_k<<<dim3(((size_t)NS * HID + 255) / 256), dim3(256), 0, stream>>>(
            acc_span, cb + 0 * HID, nullptr, NS * HID);
        init_acc_k<<<dim3(((size_t)NT * HID + 255) / 256), dim3(256), 0, stream>>>(
            acc_sent, cb + 1 * HID, cb + 2 * HID, NT * HID);
        init_acc_k<<<dim3(((size_t)NC * HID + 255) / 256), dim3(256), 0, stream>>>(
            acc_cent, cb + 3 * HID, cb + 4 * HID, NC * HID);

        for (int r = 0; r < 5; ++r) {
            const int st = rsrc[r], dt = rdst[r];
            const int Nsrc = Nn[st], Ndst = Nn[dt];
            const size_t lr = (size_t)l * 5 + r;

            launch_gemm(xbuf[st], conv_Ws + lr * HID * HID, nullptr, hs, Nsrc, HID, stream);
            rowdot_k<<<dim3(((size_t)Nsrc * 64 + 255) / 256), dim3(256), 0, stream>>>(
                hs, conv_as + lr * HID, as_s, Nsrc);
            rowdot_k<<<dim3(((size_t)Ndst * 64 + 255) / 256), dim3(256), 0, stream>>>(
                xbuf[dt], wd_all + lr * HID, ad_s, Ndst);

            gat_dst_k<<<dim3(((size_t)Ndst * 64 + 255) / 256), dim3(256), 0, stream>>>(
                row_ptr[r], col[r], as_s, ad_s, hs, racc[r], Ndst);
        }

        relu_k<<<dim3(((size_t)NS * HID + 255) / 256), dim3(256), 0, stream>>>(
            acc_span, xbuf[2], NS * HID);
        relu_k<<<dim3(((size_t)NT * HID + 255) / 256), dim3(256), 0, stream>>>(
            acc_sent, xbuf[3], NT * HID);
        relu_k<<<dim3(((size_t)NC * HID + 255) / 256), dim3(256), 0, stream>>>(
            acc_cent, xbuf[1], NC * HID);
    }

    // 3. output projection on SPAN
    out_proj_k<<<dim3(((size_t)NS * 64 + 255) / 256), dim3(256), 0, stream>>>(
        xbuf[2], out_W, out_b, (float*)d_out, NS);
}

// Round 3
// 1292.153 us; speedup vs baseline: 1.6176x; 1.3752x over previous
//
#include <hip/hip_runtime.h>

#define IN_DIM 256
#define HID 128

struct EdgeTab {
    const int* src[5];
    const int* dst[5];
    int ebase[6];  // cumulative edge offsets
    int rbase[6];  // cumulative dst-node offsets
};

// ---------- fp32 tiled GEMM: C[N,128] = A[N,K] @ W[K,128] (+bias) ----------
template <int K>
__global__ __launch_bounds__(256) void gemm_nk(const float* __restrict__ A,
                                               const float* __restrict__ W,
                                               const float* __restrict__ bias,
                                               float* __restrict__ C, int N) {
    __shared__ float As[32][68];
    __shared__ float Ws[32][128];
    const int tid = threadIdx.x;
    const int block_row = blockIdx.x * 64;
    const int tx = tid & 31;
    const int ty = tid >> 5;

    float acc[8][4];
#pragma unroll
    for (int i = 0; i < 8; ++i)
#pragma unroll
        for (int j = 0; j < 4; ++j) acc[i][j] = 0.f;

    const int lc = tid & 7;
    const int lr = tid >> 3;

    for (int k0 = 0; k0 < K; k0 += 32) {
#pragma unroll
        for (int rr = lr; rr < 64; rr += 32) {
            const int grow = block_row + rr;
            float4 v = make_float4(0.f, 0.f, 0.f, 0.f);
            if (grow < N)
                v = *reinterpret_cast<const float4*>(A + (size_t)grow * K + k0 + lc * 4);
            As[lc * 4 + 0][rr] = v.x;
            As[lc * 4 + 1][rr] = v.y;
            As[lc * 4 + 2][rr] = v.z;
            As[lc * 4 + 3][rr] = v.w;
        }
#pragma unroll
        for (int kk = ty; kk < 32; kk += 8) {
            *reinterpret_cast<float4*>(&Ws[kk][tx * 4]) =
                *reinterpret_cast<const float4*>(W + (size_t)(k0 + kk) * HID + tx * 4);
        }
        __syncthreads();
#pragma unroll
        for (int kk = 0; kk < 32; ++kk) {
            const float4 a0 = *reinterpret_cast<const float4*>(&As[kk][ty * 8]);
            const float4 a1 = *reinterpret_cast<const float4*>(&As[kk][ty * 8 + 4]);
            const float4 b = *reinterpret_cast<const float4*>(&Ws[kk][tx * 4]);
            const float av[8] = {a0.x, a0.y, a0.z, a0.w, a1.x, a1.y, a1.z, a1.w};
            const float bv[4] = {b.x, b.y, b.z, b.w};
#pragma unroll
            for (int i = 0; i < 8; ++i)
#pragma unroll
                for (int j = 0; j < 4; ++j) acc[i][j] += av[i] * bv[j];
        }
        __syncthreads();
    }

    float badd[4] = {0.f, 0.f, 0.f, 0.f};
    if (bias) {
        badd[0] = bias[tx * 4 + 0];
        badd[1] = bias[tx * 4 + 1];
        badd[2] = bias[tx * 4 + 2];
        badd[3] = bias[tx * 4 + 3];
    }
#pragma unroll
    for (int i = 0; i < 8; ++i) {
        const int grow = block_row + ty * 8 + i;
        if (grow < N) {
            float4 o;
            o.x = acc[i][0] + badd[0];
            o.y = acc[i][1] + badd[1];
            o.z = acc[i][2] + badd[2];
            o.w = acc[i][3] + badd[3];
            *reinterpret_cast<float4*>(C + (size_t)grow * HID + tx * 4) = o;
        }
    }
}

// ---------- out[row] = dot(X[row,:128], v[:128]) (wave per row) ----------
__global__ __launch_bounds__(256) void rowdot_k(const float* __restrict__ X,
                                                const float* __restrict__ v,
                                                float* __restrict__ out, int N) {
    const int idx = blockIdx.x * blockDim.x + threadIdx.x;
    const int row = idx >> 6;
    const int lane = threadIdx.x & 63;
    if (row >= N) return;
    const float* x = X + (size_t)row * HID;
    float p = x[lane] * v[lane] + x[lane + 64] * v[lane + 64];
#pragma unroll
    for (int off = 32; off > 0; off >>= 1) p += __shfl_xor(p, off, 64);
    if (lane == 0) out[row] = p;
}

// ---------- wd_all[lr][k] = dot(Wd[lr][k][:], ad[lr][:]) ----------
__global__ __launch_bounds__(256) void wdvec_k(const float* __restrict__ Wd,
                                               const float* __restrict__ ad,
                                               float* __restrict__ wd_all) {
    const int idx = blockIdx.x * blockDim.x + threadIdx.x;
    const int row = idx >> 6;  // 0..1279
    const int lane = threadIdx.x & 63;
    if (row >= 10 * HID) return;
    const int lr = row >> 7;
    const float* w = Wd + (size_t)row * HID;
    const float* a = ad + (size_t)lr * HID;
    float p = w[lane] * a[lane] + w[lane + 64] * a[lane + 64];
#pragma unroll
    for (int off = 32; off > 0; off >>= 1) p += __shfl_xor(p, off, 64);
    if (lane == 0) wd_all[row] = p;
}

// ---------- final: out[row] = dot(X[row,:], w) + b[0] ----------
__global__ __launch_bounds__(256) void out_proj_k(const float* __restrict__ X,
                                                  const float* __restrict__ w,
                                                  const float* __restrict__ b,
                                                  float* __restrict__ out, int N) {
    const int idx = blockIdx.x * blockDim.x + threadIdx.x;
    const int row = idx >> 6;
    const int lane = threadIdx.x & 63;
    if (row >= N) return;
    const float* x = X + (size_t)row * HID;
    float p = x[lane] * w[lane] + x[lane + 64] * w[lane + 64];
#pragma unroll
    for (int off = 32; off > 0; off >>= 1) p += __shfl_xor(p, off, 64);
    if (lane == 0) out[row] = p + b[0];
}

// ================= concatenated CSR build (all 5 relations at once) ==========
__global__ __launch_bounds__(256) void hist_all_k(EdgeTab t, int* __restrict__ deg,
                                                  int totalE) {
    const int idx = blockIdx.x * blockDim.x + threadIdx.x;
    if (idx >= totalE) return;
    int r = 0;
    while (idx >= t.ebase[r + 1]) ++r;
    const int e = idx - t.ebase[r];
    atomicAdd(deg + t.rbase[r] + t.dst[r][e], 1);
}

// stage 1: per-block (1024 elems) partial sums
__global__ __launch_bounds__(256) void scan_partial_k(const int* __restrict__ deg,
                                                      int* __restrict__ partial, int total) {
    const int tid = threadIdx.x;
    const int base = blockIdx.x * 1024 + tid * 4;
    int s = 0;
#pragma unroll
    for (int i = 0; i < 4; ++i) {
        const int idx = base + i;
        if (idx < total) s += deg[idx];
    }
    __shared__ int red[4];
    int w = s;
#pragma unroll
    for (int off = 32; off > 0; off >>= 1) w += __shfl_xor(w, off, 64);
    if ((tid & 63) == 0) red[tid >> 6] = w;
    __syncthreads();
    if (tid == 0) partial[blockIdx.x] = red[0] + red[1] + red[2] + red[3];
}

// stage 2: exclusive scan of <=256 partials, in place, single block
__global__ __launch_bounds__(256) void scan_partials_k(int* __restrict__ partial, int nb) {
    __shared__ int sc[256];
    const int tid = threadIdx.x;
    const int v = (tid < nb) ? partial[tid] : 0;
    sc[tid] = v;
    __syncthreads();
    for (int off = 1; off < 256; off <<= 1) {
        const int u = (tid >= off) ? sc[tid - off] : 0;
        __syncthreads();
        sc[tid] += u;
        __syncthreads();
    }
    if (tid < nb) partial[tid] = sc[tid] - v;  // exclusive
}

// stage 3: per-block local exclusive scan + global offset -> row_ptr & cursor
__global__ __launch_bounds__(256) void scan_write_k(const int* __restrict__ deg,
                                                    const int* __restrict__ partial,
                                                    int* __restrict__ row_ptr,
                                                    int* __restrict__ cursor, int total,
                                                    int grand_total) {
    const int tid = threadIdx.x;
    const int base = blockIdx.x * 1024 + tid * 4;
    int v[4];
    int s = 0;
#pragma unroll
    for (int i = 0; i < 4; ++i) {
        const int idx = base + i;
        v[i] = (idx < total) ? deg[idx] : 0;
        s += v[i];
    }
    __shared__ int sc[256];
    sc[tid] = s;
    __syncthreads();
    for (int off = 1; off < 256; off <<= 1) {
        const int u = (tid >= off) ? sc[tid - off] : 0;
        __syncthreads();
        sc[tid] += u;
        __syncthreads();
    }
    int run = partial[blockIdx.x] + sc[tid] - s;  // exclusive prefix for this thread
#pragma unroll
    for (int i = 0; i < 4; ++i) {
        const int idx = base + i;
        if (idx < total) {
            row_ptr[idx] = run;
            cursor[idx] = run;
            run += v[i];
        }
    }
    if (blockIdx.x == 0 && tid == 0) row_ptr[total] = grand_total;
}

__global__ __launch_bounds__(256) void scatter_all_k(EdgeTab t, int* __restrict__ cursor,
                                                     int* __restrict__ col_all, int totalE) {
    const int idx = blockIdx.x * blockDim.x + threadIdx.x;
    if (idx >= totalE) return;
    int r = 0;
    while (idx >= t.ebase[r + 1]) ++r;
    const int e = idx - t.ebase[r];
    const int pos = atomicAdd(cursor + t.rbase[r] + t.dst[r][e], 1);
    col_all[pos] = t.src[r][e];
}

// ========== fused per-dst GAT: softmax + weighted gather, 1 wave / dst =======
__global__ __launch_bounds__(256) void gat_dst_k(const int* __restrict__ row_ptr,
                                                 const int* __restrict__ col,
                                                 const float* __restrict__ as_s,
                                                 const float* __restrict__ ad_s,
                                                 const float* __restrict__ hs,
                                                 float* __restrict__ out, int Ndst) {
    const int idx = blockIdx.x * blockDim.x + threadIdx.x;
    const int row = idx >> 6;
    const int lane = threadIdx.x & 63;
    if (row >= Ndst) return;
    const int beg = row_ptr[row];
    const int end = row_ptr[row + 1];
    if (beg == end) return;  // no edges: out keeps its bias preinit
    const float ad = ad_s[row];

    // pass 1: segment max (lane-distributed)
    float m = -INFINITY;
    for (int e = beg + lane; e < end; e += 64) {
        float ev = as_s[col[e]] + ad;
        ev = ev > 0.f ? ev : 0.2f * ev;
        m = fmaxf(m, ev);
    }
#pragma unroll
    for (int off = 32; off > 0; off >>= 1) m = fmaxf(m, __shfl_xor(m, off, 64));

    // pass 2: denom (lane-distributed)
    float dsum = 0.f;
    for (int e = beg + lane; e < end; e += 64) {
        float ev = as_s[col[e]] + ad;
        ev = ev > 0.f ? ev : 0.2f * ev;
        dsum += expf(ev - m);
    }
#pragma unroll
    for (int off = 32; off > 0; off >>= 1) dsum += __shfl_xor(dsum, off, 64);
    const float inv = 1.f / (dsum + 1e-16f);

    // pass 3: serial over edges, wave-wide coalesced gather of hs rows
    float a0 = 0.f, a1 = 0.f;
    for (int e = beg; e < end; ++e) {
        const int s = col[e];  // same addr all lanes -> broadcast
        float ev = as_s[s] + ad;
        ev = ev > 0.f ? ev : 0.2f * ev;
        const float alpha = expf(ev - m) * inv;
        const float* h = hs + (size_t)s * HID;
        a0 += alpha * h[lane];
        a1 += alpha * h[lane + 64];
    }
    float* orow = out + (size_t)row * HID;
    orow[lane] += a0;
    orow[lane + 64] += a1;
}

// ---------- acc init: acc[i] = b1[i%128] (+ b2[i%128]) ----------
__global__ __launch_bounds__(256) void init_acc_k(float* __restrict__ acc,
                                                  const float* __restrict__ b1,
                                                  const float* __restrict__ b2, int total) {
    const int i = blockIdx.x * blockDim.x + threadIdx.x;
    if (i >= total) return;
    const int c = i & (HID - 1);
    float v = b1[c];
    if (b2) v += b2[c];
    acc[i] = v;
}

__global__ __launch_bounds__(256) void relu_k(const float* __restrict__ a,
                                              float* __restrict__ x, int total) {
    const int i = blockIdx.x * blockDim.x + threadIdx.x;
    if (i < total) x[i] = fmaxf(a[i], 0.f);
}

static inline void launch_gemm(const float* A, const float* W, const float* bias, float* C,
                               int N, int K, hipStream_t s) {
    dim3 g((N + 63) / 64), b(256);
    if (K == 256)
        gemm_nk<256><<<g, b, 0, s>>>(A, W, bias, C, N);
    else
        gemm_nk<128><<<g, b, 0, s>>>(A, W, bias, C, N);
}

extern "C" void kernel_launch(void* const* d_in, const int* in_sizes, int n_in,
                              void* d_out, int out_size, void* d_ws, size_t ws_size,
                              hipStream_t stream) {
    const float* xin[4];
    for (int i = 0; i < 4; ++i) xin[i] = (const float*)d_in[i];
    const int* eptr[5];
    int Ecnt[5];
    for (int r = 0; r < 5; ++r) {
        eptr[r] = (const int*)d_in[4 + r];
        Ecnt[r] = in_sizes[4 + r] / 2;
    }
    const float* lin_W = (const float*)d_in[9];
    const float* lin_b = (const float*)d_in[10];
    const float* conv_Ws = (const float*)d_in[11];
    const float* conv_Wd = (const float*)d_in[12];
    const float* conv_as = (const float*)d_in[13];
    const float* conv_ad = (const float*)d_in[14];
    const float* conv_b = (const float*)d_in[15];
    const float* out_W = (const float*)d_in[16];
    const float* out_b = (const float*)d_in[17];

    int Nn[4];
    for (int i = 0; i < 4; ++i) Nn[i] = in_sizes[i] / IN_DIM;  // QENT, CENT, SPAN, SENT
    const int NQ = Nn[0], NC = Nn[1], NS = Nn[2], NT = Nn[3];
    (void)NQ; (void)n_in; (void)out_size;

    int maxN = 0;
    for (int i = 0; i < 4; ++i) maxN = Nn[i] > maxN ? Nn[i] : maxN;

    // relation table: src type, dst type
    const int rsrc[5] = {0, 0, 1, 2, 1};
    const int rdst[5] = {2, 3, 3, 1, 1};

    // concatenated CSR bases
    EdgeTab tab;
    tab.ebase[0] = 0;
    tab.rbase[0] = 0;
    for (int r = 0; r < 5; ++r) {
        tab.src[r] = eptr[r];
        tab.dst[r] = eptr[r] + Ecnt[r];
        tab.ebase[r + 1] = tab.ebase[r] + Ecnt[r];
        tab.rbase[r + 1] = tab.rbase[r] + Nn[rdst[r]];
    }
    const int totalE = tab.ebase[5];
    const int totalD = tab.rbase[5];

    // ---- workspace carve ----
    float* ws = (float*)d_ws;
    size_t off = 0;
    auto alloc = [&](size_t n) { float* p = ws + off; off += n; return p; };
    float* xq = alloc((size_t)Nn[0] * HID);
    float* xc = alloc((size_t)Nn[1] * HID);
    float* xs = alloc((size_t)Nn[2] * HID);
    float* xt = alloc((size_t)Nn[3] * HID);
    float* acc_span = alloc((size_t)NS * HID);
    float* acc_sent = alloc((size_t)NT * HID);
    float* acc_cent = alloc((size_t)NC * HID);
    float* hs = alloc((size_t)maxN * HID);
    float* as_s = alloc(maxN);
    float* ad_s = alloc(maxN);
    float* wd_all = alloc(10 * HID);
    int* deg = (int*)alloc(totalD);
    int* cursor_all = (int*)alloc(totalD);
    int* row_ptr_all = (int*)alloc((size_t)totalD + 1);
    int* partial = (int*)alloc(256);
    int* col_all = (int*)alloc(totalE);
    (void)ws_size;

    float* xbuf[4] = {xq, xc, xs, xt};
    float* racc[5] = {acc_span, acc_sent, acc_sent, acc_cent, acc_cent};

    // 0. build concatenated dst-CSR (edges identical across layers)
    const int nb = (totalD + 1023) / 1024;  // <= 256 for this problem
    hipMemsetAsync(deg, 0, (size_t)totalD * 4, stream);
    hist_all_k<<<dim3((totalE + 255) / 256), dim3(256), 0, stream>>>(tab, deg, totalE);
    scan_partial_k<<<dim3(nb), dim3(256), 0, stream>>>(deg, partial, totalD);
    scan_partials_k<<<dim3(1), dim3(256), 0, stream>>>(partial, nb);
    scan_write_k<<<dim3(nb), dim3(256), 0, stream>>>(deg, partial, row_ptr_all, cursor_all,
                                                     totalD, totalE);
    scatter_all_k<<<dim3((totalE + 255) / 256), dim3(256), 0, stream>>>(tab, cursor_all,
                                                                        col_all, totalE);

    // 1. per-type input projection
    for (int t = 0; t < 4; ++t)
        launch_gemm(xin[t], lin_W + (size_t)t * IN_DIM * HID, lin_b + (size_t)t * HID,
                    xbuf[t], Nn[t], IN_DIM, stream);

    // 2. wd vectors: wd_all[l*5+r] = conv_Wd[l,r] @ conv_ad[l,r]
    wdvec_k<<<dim3((10 * HID * 64 + 255) / 256), dim3(256), 0, stream>>>(conv_Wd, conv_ad,
                                                                          wd_all);

    for (int l = 0; l < 2; ++l) {
        const float* cb = conv_b + (size_t)l * 5 * HID;
        init_acc_k<<<dim3(((size_t)NS * HID + 255) / 256), dim3(256), 0, stream>>>(
            acc_span, cb + 0 * HID, nullptr, NS * HID);
        init_acc_k<<<dim3(((size_t)NT * HID + 255) / 256), dim3(256), 0, stream>>>(
            acc_sent, cb + 1 * HID, cb + 2 * HID, NT * HID);
        init_acc_k<<<dim3(((size_t)NC * HID + 255) / 256), dim3(256), 0, stream>>>(
            acc_cent, cb + 3 * HID, cb + 4 * HID, NC * HID);

        for (int r = 0; r < 5; ++r) {
            const int st = rsrc[r], dt = rdst[r];
            const int Nsrc = Nn[st], Ndst = Nn[dt];
            const size_t lr = (size_t)l * 5 + r;

            launch_gemm(xbuf[st], conv_Ws + lr * HID * HID, nullptr, hs, Nsrc, HID, stream);
            rowdot_k<<<dim3(((size_t)Nsrc * 64 + 255) / 256), dim3(256), 0, stream>>>(
                hs, conv_as + lr * HID, as_s, Nsrc);
            rowdot_k<<<dim3(((size_t)Ndst * 64 + 255) / 256), dim3(256), 0, stream>>>(
                xbuf[dt], wd_all + lr * HID, ad_s, Ndst);

            gat_dst_k<<<dim3(((size_t)Ndst * 64 + 255) / 256), dim3(256), 0, stream>>>(
                row_ptr_all + tab.rbase[r], col_all, as_s, ad_s, hs, racc[r], Ndst);
        }

        relu_k<<<dim3(((size_t)NS * HID + 255) / 256), dim3(256), 0, stream>>>(
            acc_span, xbuf[2], NS * HID);
        relu_k<<<dim3(((size_t)NT * HID + 255) / 256), dim3(256), 0, stream>>>(
            acc_sent, xbuf[3], NT * HID);
        relu_k<<<dim3(((size_t)NC * HID + 255) / 256), dim3(256), 0, stream>>>(
            acc_cent, xbuf[1], NC * HID);
    }

    // 3. output projection on SPAN
    out_proj_k<<<dim3(((size_t)NS * 64 + 255) / 256), dim3(256), 0, stream>>>(
        xbuf[2], out_W, out_b, (float*)d_out, NS);
}

// Round 4
// 1047.230 us; speedup vs baseline: 1.9959x; 1.2339x over previous
//
#include <hip/hip_runtime.h>

#define IN_DIM 256
#define HID 128

using bf16x8 = __attribute__((ext_vector_type(8))) short;
using f32x4 = __attribute__((ext_vector_type(4))) float;

struct EdgeTab {
    const int* src[5];
    const int* dst[5];
    int ebase[6];  // cumulative edge offsets
    int rbase[6];  // cumulative dst-node offsets
};

__device__ __forceinline__ unsigned short f2bf(float f) {
    unsigned u = __float_as_uint(f);
    u += 0x7fffu + ((u >> 16) & 1u);  // RNE (inputs finite)
    return (unsigned short)(u >> 16);
}

// ---------- weight transpose+convert: W[m][K][128] fp32 -> Wt[m][K/8][128][8] bf16 ----
__global__ __launch_bounds__(256) void wtcvt_k(const float* __restrict__ W,
                                               short* __restrict__ Wt, int K, int total) {
    const int idx = blockIdx.x * blockDim.x + threadIdx.x;
    if (idx >= total) return;
    const int per = K * HID;
    const int m = idx / per;
    const int o = idx - m * per;
    const int kkblk = o >> 10;        // o / (128*8)
    const int n = (o >> 3) & 127;
    const int t = o & 7;
    const int k = (kkblk << 3) | t;
    Wt[idx] = (short)f2bf(W[(size_t)m * per + (size_t)k * HID + n]);
}

// ---------- MFMA GEMM: C[N,128] = A_fp32[N,K] @ Wt_bf16 (+bias) (+fused as) ----------
// block = 256 threads = 4 waves; BM = 64 (16 rows/wave); no LDS (weights via L1/L2).
template <int K>
__global__ __launch_bounds__(256) void gemm_mfma(const float* __restrict__ A,
                                                 const short* __restrict__ Wt,
                                                 const float* __restrict__ bias,
                                                 float* __restrict__ C,
                                                 float* __restrict__ as_out,
                                                 const float* __restrict__ a_s_vec, int N) {
    const int tid = threadIdx.x;
    const int w = tid >> 6;
    const int lane = tid & 63;
    const int m16 = lane & 15;  // M-row within frag for A; N-col for B/C
    const int kg = lane >> 4;   // k-group (0..3)

    const int arow = blockIdx.x * 64 + w * 16 + m16;
    const bool arow_ok = arow < N;

    f32x4 acc[8];
#pragma unroll
    for (int j = 0; j < 8; ++j) acc[j] = (f32x4){0.f, 0.f, 0.f, 0.f};

    for (int k0 = 0; k0 < K; k0 += 32) {
        bf16x8 af = {0, 0, 0, 0, 0, 0, 0, 0};
        if (arow_ok) {
            const float* ap = A + (size_t)arow * K + k0 + kg * 8;
            const float4 f0 = *reinterpret_cast<const float4*>(ap);
            const float4 f1 = *reinterpret_cast<const float4*>(ap + 4);
            af[0] = (short)f2bf(f0.x); af[1] = (short)f2bf(f0.y);
            af[2] = (short)f2bf(f0.z); af[3] = (short)f2bf(f0.w);
            af[4] = (short)f2bf(f1.x); af[5] = (short)f2bf(f1.y);
            af[6] = (short)f2bf(f1.z); af[7] = (short)f2bf(f1.w);
        }
        // B elems (k = k0+kg*8+t, n = j*16+m16) at ((k>>3)*128 + n)*8 + t
        const short* bbase = Wt + (((k0 >> 3) + kg) << 10);
#pragma unroll
        for (int j = 0; j < 8; ++j) {
            const bf16x8 bf = *reinterpret_cast<const bf16x8*>(bbase + ((j * 16 + m16) << 3));
            acc[j] = __builtin_amdgcn_mfma_f32_16x16x32_bf16(af, bf, acc[j], 0, 0, 0);
        }
    }

    // C/D layout: col = lane&15 (within frag j), row = kg*4 + reg
    const int rbase = blockIdx.x * 64 + w * 16 + kg * 4;

    float bj[8];
#pragma unroll
    for (int j = 0; j < 8; ++j) bj[j] = bias ? bias[j * 16 + m16] : 0.f;

#pragma unroll
    for (int j = 0; j < 8; ++j) {
#pragma unroll
        for (int r = 0; r < 4; ++r) {
            const int row = rbase + r;
            if (row < N) C[(size_t)row * HID + j * 16 + m16] = acc[j][r] + bj[j];
        }
    }

    if (as_out) {  // fused: as_out[row] = dot(C_row, a_s_vec) (pre-bias; bias==null here)
        float p0 = 0.f, p1 = 0.f, p2 = 0.f, p3 = 0.f;
#pragma unroll
        for (int j = 0; j < 8; ++j) {
            const float av = a_s_vec[j * 16 + m16];
            p0 += acc[j][0] * av;
            p1 += acc[j][1] * av;
            p2 += acc[j][2] * av;
            p3 += acc[j][3] * av;
        }
#pragma unroll
        for (int off = 8; off > 0; off >>= 1) {
            p0 += __shfl_xor(p0, off, 64);
            p1 += __shfl_xor(p1, off, 64);
            p2 += __shfl_xor(p2, off, 64);
            p3 += __shfl_xor(p3, off, 64);
        }
        if (m16 == 0) {
            if (rbase + 0 < N) as_out[rbase + 0] = p0;
            if (rbase + 1 < N) as_out[rbase + 1] = p1;
            if (rbase + 2 < N) as_out[rbase + 2] = p2;
            if (rbase + 3 < N) as_out[rbase + 3] = p3;
        }
    }
}

// ---------- out[row] = dot(X[row,:128], v[:128]) (wave per row) ----------
__global__ __launch_bounds__(256) void rowdot_k(const float* __restrict__ X,
                                                const float* __restrict__ v,
                                                float* __restrict__ out, int N) {
    const int idx = blockIdx.x * blockDim.x + threadIdx.x;
    const int row = idx >> 6;
    const int lane = threadIdx.x & 63;
    if (row >= N) return;
    const float* x = X + (size_t)row * HID;
    float p = x[lane] * v[lane] + x[lane + 64] * v[lane + 64];
#pragma unroll
    for (int off = 32; off > 0; off >>= 1) p += __shfl_xor(p, off, 64);
    if (lane == 0) out[row] = p;
}

// ---------- wd_all[lr][k] = dot(Wd[lr][k][:], ad[lr][:]) ----------
__global__ __launch_bounds__(256) void wdvec_k(const float* __restrict__ Wd,
                                               const float* __restrict__ ad,
                                               float* __restrict__ wd_all) {
    const int idx = blockIdx.x * blockDim.x + threadIdx.x;
    const int row = idx >> 6;  // 0..1279
    const int lane = threadIdx.x & 63;
    if (row >= 10 * HID) return;
    const int lr = row >> 7;
    const float* w = Wd + (size_t)row * HID;
    const float* a = ad + (size_t)lr * HID;
    float p = w[lane] * a[lane] + w[lane + 64] * a[lane + 64];
#pragma unroll
    for (int off = 32; off > 0; off >>= 1) p += __shfl_xor(p, off, 64);
    if (lane == 0) wd_all[row] = p;
}

// ---------- final: out[row] = dot(X[row,:], w) + b[0] ----------
__global__ __launch_bounds__(256) void out_proj_k(const float* __restrict__ X,
                                                  const float* __restrict__ w,
                                                  const float* __restrict__ b,
                                                  float* __restrict__ out, int N) {
    const int idx = blockIdx.x * blockDim.x + threadIdx.x;
    const int row = idx >> 6;
    const int lane = threadIdx.x & 63;
    if (row >= N) return;
    const float* x = X + (size_t)row * HID;
    float p = x[lane] * w[lane] + x[lane + 64] * w[lane + 64];
#pragma unroll
    for (int off = 32; off > 0; off >>= 1) p += __shfl_xor(p, off, 64);
    if (lane == 0) out[row] = p + b[0];
}

// ================= concatenated CSR build (all 5 relations at once) ==========
__global__ __launch_bounds__(256) void hist_all_k(EdgeTab t, int* __restrict__ deg,
                                                  int totalE) {
    const int idx = blockIdx.x * blockDim.x + threadIdx.x;
    if (idx >= totalE) return;
    int r = 0;
    while (idx >= t.ebase[r + 1]) ++r;
    const int e = idx - t.ebase[r];
    atomicAdd(deg + t.rbase[r] + t.dst[r][e], 1);
}

__global__ __launch_bounds__(256) void scan_partial_k(const int* __restrict__ deg,
                                                      int* __restrict__ partial, int total) {
    const int tid = threadIdx.x;
    const int base = blockIdx.x * 1024 + tid * 4;
    int s = 0;
#pragma unroll
    for (int i = 0; i < 4; ++i) {
        const int idx = base + i;
        if (idx < total) s += deg[idx];
    }
    __shared__ int red[4];
    int w = s;
#pragma unroll
    for (int off = 32; off > 0; off >>= 1) w += __shfl_xor(w, off, 64);
    if ((tid & 63) == 0) red[tid >> 6] = w;
    __syncthreads();
    if (tid == 0) partial[blockIdx.x] = red[0] + red[1] + red[2] + red[3];
}

__global__ __launch_bounds__(256) void scan_partials_k(int* __restrict__ partial, int nb) {
    __shared__ int sc[256];
    const int tid = threadIdx.x;
    const int v = (tid < nb) ? partial[tid] : 0;
    sc[tid] = v;
    __syncthreads();
    for (int off = 1; off < 256; off <<= 1) {
        const int u = (tid >= off) ? sc[tid - off] : 0;
        __syncthreads();
        sc[tid] += u;
        __syncthreads();
    }
    if (tid < nb) partial[tid] = sc[tid] - v;  // exclusive
}

__global__ __launch_bounds__(256) void scan_write_k(const int* __restrict__ deg,
                                                    const int* __restrict__ partial,
                                                    int* __restrict__ row_ptr,
                                                    int* __restrict__ cursor, int total,
                                                    int grand_total) {
    const int tid = threadIdx.x;
    const int base = blockIdx.x * 1024 + tid * 4;
    int v[4];
    int s = 0;
#pragma unroll
    for (int i = 0; i < 4; ++i) {
        const int idx = base + i;
        v[i] = (idx < total) ? deg[idx] : 0;
        s += v[i];
    }
    __shared__ int sc[256];
    sc[tid] = s;
    __syncthreads();
    for (int off = 1; off < 256; off <<= 1) {
        const int u = (tid >= off) ? sc[tid - off] : 0;
        __syncthreads();
        sc[tid] += u;
        __syncthreads();
    }
    int run = partial[blockIdx.x] + sc[tid] - s;
#pragma unroll
    for (int i = 0; i < 4; ++i) {
        const int idx = base + i;
        if (idx < total) {
            row_ptr[idx] = run;
            cursor[idx] = run;
            run += v[i];
        }
    }
    if (blockIdx.x == 0 && tid == 0) row_ptr[total] = grand_total;
}

__global__ __launch_bounds__(256) void scatter_all_k(EdgeTab t, int* __restrict__ cursor,
                                                     int* __restrict__ col_all, int totalE) {
    const int idx = blockIdx.x * blockDim.x + threadIdx.x;
    if (idx >= totalE) return;
    int r = 0;
    while (idx >= t.ebase[r + 1]) ++r;
    const int e = idx - t.ebase[r];
    const int pos = atomicAdd(cursor + t.rbase[r] + t.dst[r][e], 1);
    col_all[pos] = t.src[r][e];
}

// ========== fused per-dst GAT: softmax + weighted gather, 1 wave / dst =======
__global__ __launch_bounds__(256) void gat_dst_k(const int* __restrict__ row_ptr,
                                                 const int* __restrict__ col,
                                                 const float* __restrict__ as_s,
                                                 const float* __restrict__ ad_s,
                                                 const float* __restrict__ hs,
                                                 float* __restrict__ out, int Ndst) {
    const int idx = blockIdx.x * blockDim.x + threadIdx.x;
    const int row = idx >> 6;
    const int lane = threadIdx.x & 63;
    if (row >= Ndst) return;
    const int beg = row_ptr[row];
    const int end = row_ptr[row + 1];
    if (beg == end) return;
    const float ad = ad_s[row];

    float m = -INFINITY;
    for (int e = beg + lane; e < end; e += 64) {
        float ev = as_s[col[e]] + ad;
        ev = ev > 0.f ? ev : 0.2f * ev;
        m = fmaxf(m, ev);
    }
#pragma unroll
    for (int off = 32; off > 0; off >>= 1) m = fmaxf(m, __shfl_xor(m, off, 64));

    float dsum = 0.f;
    for (int e = beg + lane; e < end; e += 64) {
        float ev = as_s[col[e]] + ad;
        ev = ev > 0.f ? ev : 0.2f * ev;
        dsum += expf(ev - m);
    }
#pragma unroll
    for (int off = 32; off > 0; off >>= 1) dsum += __shfl_xor(dsum, off, 64);
    const float inv = 1.f / (dsum + 1e-16f);

    float a0 = 0.f, a1 = 0.f;
    for (int e = beg; e < end; ++e) {
        const int s = col[e];
        float ev = as_s[s] + ad;
        ev = ev > 0.f ? ev : 0.2f * ev;
        const float alpha = expf(ev - m) * inv;
        const float* h = hs + (size_t)s * HID;
        a0 += alpha * h[lane];
        a1 += alpha * h[lane + 64];
    }
    float* orow = out + (size_t)row * HID;
    orow[lane] += a0;
    orow[lane + 64] += a1;
}

// ---------- acc init ----------
__global__ __launch_bounds__(256) void init_acc_k(float* __restrict__ acc,
                                                  const float* __restrict__ b1,
                                                  const float* __restrict__ b2, int total) {
    const int i = blockIdx.x * blockDim.x + threadIdx.x;
    if (i >= total) return;
    const int c = i & (HID - 1);
    float v = b1[c];
    if (b2) v += b2[c];
    acc[i] = v;
}

__global__ __launch_bounds__(256) void relu_k(const float* __restrict__ a,
                                              float* __restrict__ x, int total) {
    const int i = blockIdx.x * blockDim.x + threadIdx.x;
    if (i < total) x[i] = fmaxf(a[i], 0.f);
}

extern "C" void kernel_launch(void* const* d_in, const int* in_sizes, int n_in,
                              void* d_out, int out_size, void* d_ws, size_t ws_size,
                              hipStream_t stream) {
    const float* xin[4];
    for (int i = 0; i < 4; ++i) xin[i] = (const float*)d_in[i];
    const int* eptr[5];
    int Ecnt[5];
    for (int r = 0; r < 5; ++r) {
        eptr[r] = (const int*)d_in[4 + r];
        Ecnt[r] = in_sizes[4 + r] / 2;
    }
    const float* lin_W = (const float*)d_in[9];
    const float* lin_b = (const float*)d_in[10];
    const float* conv_Ws = (const float*)d_in[11];
    const float* conv_Wd = (const float*)d_in[12];
    const float* conv_as = (const float*)d_in[13];
    const float* conv_ad = (const float*)d_in[14];
    const float* conv_b = (const float*)d_in[15];
    const float* out_W = (const float*)d_in[16];
    const float* out_b = (const float*)d_in[17];

    int Nn[4];
    for (int i = 0; i < 4; ++i) Nn[i] = in_sizes[i] / IN_DIM;  // QENT, CENT, SPAN, SENT
    const int NQ = Nn[0], NC = Nn[1], NS = Nn[2], NT = Nn[3];
    (void)NQ; (void)n_in; (void)out_size;

    int maxN = 0;
    for (int i = 0; i < 4; ++i) maxN = Nn[i] > maxN ? Nn[i] : maxN;

    const int rsrc[5] = {0, 0, 1, 2, 1};
    const int rdst[5] = {2, 3, 3, 1, 1};

    EdgeTab tab;
    tab.ebase[0] = 0;
    tab.rbase[0] = 0;
    for (int r = 0; r < 5; ++r) {
        tab.src[r] = eptr[r];
        tab.dst[r] = eptr[r] + Ecnt[r];
        tab.ebase[r + 1] = tab.ebase[r] + Ecnt[r];
        tab.rbase[r + 1] = tab.rbase[r] + Nn[rdst[r]];
    }
    const int totalE = tab.ebase[5];
    const int totalD = tab.rbase[5];

    // ---- workspace carve ----
    float* ws = (float*)d_ws;
    size_t off = 0;
    auto alloc = [&](size_t n) { float* p = ws + off; off += n; return p; };
    float* xq = alloc((size_t)Nn[0] * HID);
    float* xc = alloc((size_t)Nn[1] * HID);
    float* xs = alloc((size_t)Nn[2] * HID);
    float* xt = alloc((size_t)Nn[3] * HID);
    float* acc_span = alloc((size_t)NS * HID);
    float* acc_sent = alloc((size_t)NT * HID);
    float* acc_cent = alloc((size_t)NC * HID);
    float* hs = alloc((size_t)maxN * HID);
    float* as_s = alloc(maxN);
    float* ad_s = alloc(maxN);
    float* wd_all = alloc(10 * HID);
    int* deg = (int*)alloc(totalD);
    int* cursor_all = (int*)alloc(totalD);
    int* row_ptr_all = (int*)alloc((size_t)totalD + 1);
    int* partial = (int*)alloc(256);
    int* col_all = (int*)alloc(totalE);
    short* wt_lin = (short*)alloc(4 * IN_DIM * HID / 2);   // bf16, [4][K/8][128][8]
    short* wt_conv = (short*)alloc(10 * HID * HID / 2);    // bf16, [10][K/8][128][8]
    (void)ws_size;

    float* xbuf[4] = {xq, xc, xs, xt};
    float* racc[5] = {acc_span, acc_sent, acc_sent, acc_cent, acc_cent};

    // 0a. weight transpose+convert (tiny)
    wtcvt_k<<<dim3((4 * IN_DIM * HID + 255) / 256), dim3(256), 0, stream>>>(
        lin_W, wt_lin, IN_DIM, 4 * IN_DIM * HID);
    wtcvt_k<<<dim3((10 * HID * HID + 255) / 256), dim3(256), 0, stream>>>(
        conv_Ws, wt_conv, HID, 10 * HID * HID);

    // 0b. concatenated dst-CSR (edges identical across layers)
    const int nb = (totalD + 1023) / 1024;
    hipMemsetAsync(deg, 0, (size_t)totalD * 4, stream);
    hist_all_k<<<dim3((totalE + 255) / 256), dim3(256), 0, stream>>>(tab, deg, totalE);
    scan_partial_k<<<dim3(nb), dim3(256), 0, stream>>>(deg, partial, totalD);
    scan_partials_k<<<dim3(1), dim3(256), 0, stream>>>(partial, nb);
    scan_write_k<<<dim3(nb), dim3(256), 0, stream>>>(deg, partial, row_ptr_all, cursor_all,
                                                     totalD, totalE);
    scatter_all_k<<<dim3((totalE + 255) / 256), dim3(256), 0, stream>>>(tab, cursor_all,
                                                                        col_all, totalE);

    // 1. per-type input projection (bf16 MFMA)
    for (int t = 0; t < 4; ++t)
        gemm_mfma<IN_DIM><<<dim3((Nn[t] + 63) / 64), dim3(256), 0, stream>>>(
            xin[t], wt_lin + (size_t)t * IN_DIM * HID, lin_b + (size_t)t * HID, xbuf[t],
            nullptr, nullptr, Nn[t]);

    // 2. wd vectors
    wdvec_k<<<dim3((10 * HID * 64 + 255) / 256), dim3(256), 0, stream>>>(conv_Wd, conv_ad,
                                                                          wd_all);

    for (int l = 0; l < 2; ++l) {
        const float* cb = conv_b + (size_t)l * 5 * HID;
        init_acc_k<<<dim3(((size_t)NS * HID + 255) / 256), dim3(256), 0, stream>>>(
            acc_span, cb + 0 * HID, nullptr, NS * HID);
        init_acc_k<<<dim3(((size_t)NT * HID + 255) / 256), dim3(256), 0, stream>>>(
            acc_sent, cb + 1 * HID, cb + 2 * HID, NT * HID);
        init_acc_k<<<dim3(((size_t)NC * HID + 255) / 256), dim3(256), 0, stream>>>(
            acc_cent, cb + 3 * HID, cb + 4 * HID, NC * HID);

        for (int r = 0; r < 5; ++r) {
            const int st = rsrc[r], dt = rdst[r];
            const int Nsrc = Nn[st], Ndst = Nn[dt];
            const size_t lr = (size_t)l * 5 + r;

            // hs = x[st] @ Ws  with fused as_s = hs @ a_s
            gemm_mfma<HID><<<dim3((Nsrc + 63) / 64), dim3(256), 0, stream>>>(
                xbuf[st], wt_conv + lr * HID * HID, nullptr, hs, as_s,
                conv_as + lr * HID, Nsrc);
            rowdot_k<<<dim3(((size_t)Ndst * 64 + 255) / 256), dim3(256), 0, stream>>>(
                xbuf[dt], wd_all + lr * HID, ad_s, Ndst);

            gat_dst_k<<<dim3(((size_t)Ndst * 64 + 255) / 256), dim3(256), 0, stream>>>(
                row_ptr_all + tab.rbase[r], col_all, as_s, ad_s, hs, racc[r], Ndst);
        }

        relu_k<<<dim3(((size_t)NS * HID + 255) / 256), dim3(256), 0, stream>>>(
            acc_span, xbuf[2], NS * HID);
        relu_k<<<dim3(((size_t)NT * HID + 255) / 256), dim3(256), 0, stream>>>(
            acc_sent, xbuf[3], NT * HID);
        relu_k<<<dim3(((size_t)NC * HID + 255) / 256), dim3(256), 0, stream>>>(
            acc_cent, xbuf[1], NC * HID);
    }

    // 3. output projection on SPAN
    out_proj_k<<<dim3(((size_t)NS * 64 + 255) / 256), dim3(256), 0, stream>>>(
        xbuf[2], out_W, out_b, (float*)d_out, NS);
}

// Round 5
// 203.032 us; speedup vs baseline: 10.2949x; 5.1580x over previous
//
#include <hip/hip_runtime.h>

#define IN_DIM 256
#define HID 128

using bf16x8 = __attribute__((ext_vector_type(8))) short;
using f32x4 = __attribute__((ext_vector_type(4))) float;

__device__ __forceinline__ unsigned short f2bf(float f) {
    unsigned u = __float_as_uint(f);
    u += 0x7fffu + ((u >> 16) & 1u);  // RNE (inputs finite)
    return (unsigned short)(u >> 16);
}

// ---------- weight transpose+convert: W[K][128] fp32 -> Wt[K/8][128][8] bf16 ----------
__global__ __launch_bounds__(256) void wtcvt_k(const float* __restrict__ W,
                                               short* __restrict__ Wt, int total) {
    const int idx = blockIdx.x * blockDim.x + threadIdx.x;
    if (idx >= total) return;
    const int kkblk = idx >> 10;  // idx / (128*8)
    const int n = (idx >> 3) & 127;
    const int t = idx & 7;
    const int k = (kkblk << 3) | t;
    Wt[idx] = (short)f2bf(W[(size_t)k * HID + n]);
}

// ---------- MFMA GEMM: C[N,128] = A_fp32[N,K] @ Wt_bf16 (+bias) (+fused as) ----------
// 256 thr = 4 waves; BM=64 (16 rows/wave); no LDS (weights via L1/L2).
template <int K>
__global__ __launch_bounds__(256) void gemm_mfma(const float* __restrict__ A,
                                                 const short* __restrict__ Wt,
                                                 const float* __restrict__ bias,
                                                 float* __restrict__ C,
                                                 float* __restrict__ as_out,
                                                 const float* __restrict__ a_s_vec, int N) {
    const int tid = threadIdx.x;
    const int w = tid >> 6;
    const int lane = tid & 63;
    const int m16 = lane & 15;
    const int kg = lane >> 4;

    const int arow = blockIdx.x * 64 + w * 16 + m16;
    const bool arow_ok = arow < N;

    f32x4 acc[8];
#pragma unroll
    for (int j = 0; j < 8; ++j) acc[j] = (f32x4){0.f, 0.f, 0.f, 0.f};

    for (int k0 = 0; k0 < K; k0 += 32) {
        bf16x8 af = {0, 0, 0, 0, 0, 0, 0, 0};
        if (arow_ok) {
            const float* ap = A + (size_t)arow * K + k0 + kg * 8;
            const float4 f0 = *reinterpret_cast<const float4*>(ap);
            const float4 f1 = *reinterpret_cast<const float4*>(ap + 4);
            af[0] = (short)f2bf(f0.x); af[1] = (short)f2bf(f0.y);
            af[2] = (short)f2bf(f0.z); af[3] = (short)f2bf(f0.w);
            af[4] = (short)f2bf(f1.x); af[5] = (short)f2bf(f1.y);
            af[6] = (short)f2bf(f1.z); af[7] = (short)f2bf(f1.w);
        }
        const short* bbase = Wt + (((k0 >> 3) + kg) << 10);
#pragma unroll
        for (int j = 0; j < 8; ++j) {
            const bf16x8 bf = *reinterpret_cast<const bf16x8*>(bbase + ((j * 16 + m16) << 3));
            acc[j] = __builtin_amdgcn_mfma_f32_16x16x32_bf16(af, bf, acc[j], 0, 0, 0);
        }
    }

    // C/D layout: col = j*16 + (lane&15), row = kg*4 + reg
    const int rbase = blockIdx.x * 64 + w * 16 + kg * 4;

    float bj[8];
#pragma unroll
    for (int j = 0; j < 8; ++j) bj[j] = bias ? bias[j * 16 + m16] : 0.f;

#pragma unroll
    for (int j = 0; j < 8; ++j) {
#pragma unroll
        for (int r = 0; r < 4; ++r) {
            const int row = rbase + r;
            if (row < N) C[(size_t)row * HID + j * 16 + m16] = acc[j][r] + bj[j];
        }
    }

    if (as_out) {  // fused: as_out[row] = dot(C_row(pre-bias), a_s_vec)
        float p0 = 0.f, p1 = 0.f, p2 = 0.f, p3 = 0.f;
#pragma unroll
        for (int j = 0; j < 8; ++j) {
            const float av = a_s_vec[j * 16 + m16];
            p0 += acc[j][0] * av;
            p1 += acc[j][1] * av;
            p2 += acc[j][2] * av;
            p3 += acc[j][3] * av;
        }
#pragma unroll
        for (int off = 8; off > 0; off >>= 1) {
            p0 += __shfl_xor(p0, off, 64);
            p1 += __shfl_xor(p1, off, 64);
            p2 += __shfl_xor(p2, off, 64);
            p3 += __shfl_xor(p3, off, 64);
        }
        if (m16 == 0) {
            if (rbase + 0 < N) as_out[rbase + 0] = p0;
            if (rbase + 1 < N) as_out[rbase + 1] = p1;
            if (rbase + 2 < N) as_out[rbase + 2] = p2;
            if (rbase + 3 < N) as_out[rbase + 3] = p3;
        }
    }
}

// ---------- wd[l*128+j] = dot(conv_Wd[l,0,j,:], conv_ad[l,0,:]) for l in {0,1} ----------
__global__ __launch_bounds__(256) void wd2_k(const float* __restrict__ Wd,
                                             const float* __restrict__ ad,
                                             float* __restrict__ wd_out) {
    const int idx = blockIdx.x * blockDim.x + threadIdx.x;
    const int row = idx >> 6;  // 0..255 : l = row>>7, j = row&127
    const int lane = threadIdx.x & 63;
    if (row >= 2 * HID) return;
    const int l = row >> 7;
    const int j = row & 127;
    const float* w = Wd + ((size_t)(l * 5) * HID + j) * HID;
    const float* a = ad + (size_t)(l * 5) * HID;
    float p = w[lane] * a[lane] + w[lane + 64] * a[lane + 64];
#pragma unroll
    for (int off = 32; off > 0; off >>= 1) p += __shfl_xor(p, off, 64);
    if (lane == 0) wd_out[row] = p;
}

// ================= CSR build for the single live relation ==========
__global__ __launch_bounds__(256) void hist_k(const int* __restrict__ dst,
                                              int* __restrict__ deg, int E) {
    const int e = blockIdx.x * blockDim.x + threadIdx.x;
    if (e < E) atomicAdd(deg + dst[e], 1);
}

__global__ __launch_bounds__(256) void scan_partial_k(const int* __restrict__ deg,
                                                      int* __restrict__ partial, int total) {
    const int tid = threadIdx.x;
    const int base = blockIdx.x * 1024 + tid * 4;
    int s = 0;
#pragma unroll
    for (int i = 0; i < 4; ++i) {
        const int idx = base + i;
        if (idx < total) s += deg[idx];
    }
    __shared__ int red[4];
    int w = s;
#pragma unroll
    for (int off = 32; off > 0; off >>= 1) w += __shfl_xor(w, off, 64);
    if ((tid & 63) == 0) red[tid >> 6] = w;
    __syncthreads();
    if (tid == 0) partial[blockIdx.x] = red[0] + red[1] + red[2] + red[3];
}

__global__ __launch_bounds__(256) void scan_partials_k(int* __restrict__ partial, int nb) {
    __shared__ int sc[256];
    const int tid = threadIdx.x;
    const int v = (tid < nb) ? partial[tid] : 0;
    sc[tid] = v;
    __syncthreads();
    for (int off = 1; off < 256; off <<= 1) {
        const int u = (tid >= off) ? sc[tid - off] : 0;
        __syncthreads();
        sc[tid] += u;
        __syncthreads();
    }
    if (tid < nb) partial[tid] = sc[tid] - v;  // exclusive
}

__global__ __launch_bounds__(256) void scan_write_k(const int* __restrict__ deg,
                                                    const int* __restrict__ partial,
                                                    int* __restrict__ row_ptr,
                                                    int* __restrict__ cursor, int total,
                                                    int grand_total) {
    const int tid = threadIdx.x;
    const int base = blockIdx.x * 1024 + tid * 4;
    int v[4];
    int s = 0;
#pragma unroll
    for (int i = 0; i < 4; ++i) {
        const int idx = base + i;
        v[i] = (idx < total) ? deg[idx] : 0;
        s += v[i];
    }
    __shared__ int sc[256];
    sc[tid] = s;
    __syncthreads();
    for (int off = 1; off < 256; off <<= 1) {
        const int u = (tid >= off) ? sc[tid - off] : 0;
        __syncthreads();
        sc[tid] += u;
        __syncthreads();
    }
    int run = partial[blockIdx.x] + sc[tid] - s;
#pragma unroll
    for (int i = 0; i < 4; ++i) {
        const int idx = base + i;
        if (idx < total) {
            row_ptr[idx] = run;
            cursor[idx] = run;
            run += v[i];
        }
    }
    if (blockIdx.x == 0 && tid == 0) row_ptr[total] = grand_total;
}

__global__ __launch_bounds__(256) void scatter_k(const int* __restrict__ src,
                                                 const int* __restrict__ dst,
                                                 int* __restrict__ cursor,
                                                 int* __restrict__ col, int E) {
    const int e = blockIdx.x * blockDim.x + threadIdx.x;
    if (e >= E) return;
    const int pos = atomicAdd(cursor + dst[e], 1);
    col[pos] = src[e];
}

// ========== fully fused per-dst GAT (SPAN): ad-dot + softmax + gather + bias
// + ReLU; layer1 updates xs in place, layer2 (FINAL) writes out = x·outW+outb =====
template <bool FINAL>
__global__ __launch_bounds__(256) void gat_span_k(const int* __restrict__ row_ptr,
                                                  const int* __restrict__ col,
                                                  const float* __restrict__ as_s,
                                                  const float* __restrict__ hs,
                                                  float* __restrict__ xs,
                                                  const float* __restrict__ wd,
                                                  const float* __restrict__ bias,
                                                  const float* __restrict__ outW,
                                                  const float* __restrict__ outb,
                                                  float* __restrict__ out, int Ndst) {
    const int idx = blockIdx.x * blockDim.x + threadIdx.x;
    const int row = idx >> 6;
    const int lane = threadIdx.x & 63;
    if (row >= Ndst) return;

    float* xrow = xs + (size_t)row * HID;
    const float xv0 = xrow[lane];
    const float xv1 = xrow[lane + 64];

    // ad = dot(x_dst_row, wd)
    float ad = xv0 * wd[lane] + xv1 * wd[lane + 64];
#pragma unroll
    for (int off = 32; off > 0; off >>= 1) ad += __shfl_xor(ad, off, 64);

    const int beg = row_ptr[row];
    const int end = row_ptr[row + 1];

    // segment max
    float m = -INFINITY;
    for (int e = beg + lane; e < end; e += 64) {
        float ev = as_s[col[e]] + ad;
        ev = ev > 0.f ? ev : 0.2f * ev;
        m = fmaxf(m, ev);
    }
#pragma unroll
    for (int off = 32; off > 0; off >>= 1) m = fmaxf(m, __shfl_xor(m, off, 64));

    // denom
    float dsum = 0.f;
    for (int e = beg + lane; e < end; e += 64) {
        float ev = as_s[col[e]] + ad;
        ev = ev > 0.f ? ev : 0.2f * ev;
        dsum += expf(ev - m);
    }
#pragma unroll
    for (int off = 32; off > 0; off >>= 1) dsum += __shfl_xor(dsum, off, 64);
    const float inv = 1.f / (dsum + 1e-16f);

    // weighted gather (serial over ~6 edges, wave-wide 512B row reads)
    float a0 = 0.f, a1 = 0.f;
    for (int e = beg; e < end; ++e) {
        const int s = col[e];
        float ev = as_s[s] + ad;
        ev = ev > 0.f ? ev : 0.2f * ev;
        const float alpha = expf(ev - m) * inv;
        const float* h = hs + (size_t)s * HID;
        a0 += alpha * h[lane];
        a1 += alpha * h[lane + 64];
    }

    const float v0 = fmaxf(a0 + bias[lane], 0.f);
    const float v1 = fmaxf(a1 + bias[lane + 64], 0.f);

    if (FINAL) {
        float p = v0 * outW[lane] + v1 * outW[lane + 64];
#pragma unroll
        for (int off = 32; off > 0; off >>= 1) p += __shfl_xor(p, off, 64);
        if (lane == 0) out[row] = p + outb[0];
    } else {
        xrow[lane] = v0;
        xrow[lane + 64] = v1;
    }
}

extern "C" void kernel_launch(void* const* d_in, const int* in_sizes, int n_in,
                              void* d_out, int out_size, void* d_ws, size_t ws_size,
                              hipStream_t stream) {
    // Live dataflow: out = SPAN_l2 @ out_W; SPAN only receives QENT->SPAN (r0);
    // QENT never updates. Everything CENT/SENT is dead code.
    const float* x_qent = (const float*)d_in[0];
    const float* x_span = (const float*)d_in[2];
    const int* e_qs = (const int*)d_in[4];  // [2][E]
    const float* lin_W = (const float*)d_in[9];
    const float* lin_b = (const float*)d_in[10];
    const float* conv_Ws = (const float*)d_in[11];
    const float* conv_Wd = (const float*)d_in[12];
    const float* conv_as = (const float*)d_in[13];
    const float* conv_ad = (const float*)d_in[14];
    const float* conv_b = (const float*)d_in[15];
    const float* out_W = (const float*)d_in[16];
    const float* out_b = (const float*)d_in[17];

    const int NQ = in_sizes[0] / IN_DIM;
    const int NS = in_sizes[2] / IN_DIM;
    const int E = in_sizes[4] / 2;
    const int* srcp = e_qs;
    const int* dstp = e_qs + E;
    (void)n_in; (void)out_size;

    // ---- workspace carve ----
    float* ws = (float*)d_ws;
    size_t off = 0;
    auto alloc = [&](size_t n) { float* p = ws + off; off += n; return p; };
    float* xq = alloc((size_t)NQ * HID);
    float* xs = alloc((size_t)NS * HID);
    float* hs = alloc((size_t)NQ * HID);
    float* as_s = alloc(NQ);
    float* wd2 = alloc(2 * HID);
    int* deg = (int*)alloc(NS);
    int* cursor = (int*)alloc(NS);
    int* row_ptr = (int*)alloc((size_t)NS + 1);
    int* partial = (int*)alloc(256);
    int* col = (int*)alloc(E);
    short* wt_lin0 = (short*)alloc(IN_DIM * HID / 2);
    short* wt_lin2 = (short*)alloc(IN_DIM * HID / 2);
    short* wt_conv0 = (short*)alloc(HID * HID / 2);
    short* wt_conv5 = (short*)alloc(HID * HID / 2);
    (void)ws_size;

    // 0a. weight transpose+convert (live slices only)
    wtcvt_k<<<dim3((IN_DIM * HID + 255) / 256), dim3(256), 0, stream>>>(
        lin_W + 0 * IN_DIM * HID, wt_lin0, IN_DIM * HID);
    wtcvt_k<<<dim3((IN_DIM * HID + 255) / 256), dim3(256), 0, stream>>>(
        lin_W + 2 * (size_t)IN_DIM * HID, wt_lin2, IN_DIM * HID);
    wtcvt_k<<<dim3((HID * HID + 255) / 256), dim3(256), 0, stream>>>(
        conv_Ws + 0 * (size_t)HID * HID, wt_conv0, HID * HID);
    wtcvt_k<<<dim3((HID * HID + 255) / 256), dim3(256), 0, stream>>>(
        conv_Ws + 5 * (size_t)HID * HID, wt_conv5, HID * HID);

    // 0b. dst-CSR for r0 (identical both layers)
    const int nb = (NS + 1023) / 1024;
    hipMemsetAsync(deg, 0, (size_t)NS * 4, stream);
    hist_k<<<dim3((E + 255) / 256), dim3(256), 0, stream>>>(dstp, deg, E);
    scan_partial_k<<<dim3(nb), dim3(256), 0, stream>>>(deg, partial, NS);
    scan_partials_k<<<dim3(1), dim3(256), 0, stream>>>(partial, nb);
    scan_write_k<<<dim3(nb), dim3(256), 0, stream>>>(deg, partial, row_ptr, cursor, NS, E);
    scatter_k<<<dim3((E + 255) / 256), dim3(256), 0, stream>>>(srcp, dstp, cursor, col, E);

    // 1. input projections (QENT, SPAN only)
    gemm_mfma<IN_DIM><<<dim3((NQ + 63) / 64), dim3(256), 0, stream>>>(
        x_qent, wt_lin0, lin_b + 0 * HID, xq, nullptr, nullptr, NQ);
    gemm_mfma<IN_DIM><<<dim3((NS + 63) / 64), dim3(256), 0, stream>>>(
        x_span, wt_lin2, lin_b + 2 * HID, xs, nullptr, nullptr, NS);

    // 2. wd vectors for (l,r=0), l in {0,1}
    wd2_k<<<dim3((2 * HID * 64 + 255) / 256), dim3(256), 0, stream>>>(conv_Wd, conv_ad, wd2);

    // 3. two layers of QENT->SPAN GAT
    const short* wtc[2] = {wt_conv0, wt_conv5};
    for (int l = 0; l < 2; ++l) {
        gemm_mfma<HID><<<dim3((NQ + 63) / 64), dim3(256), 0, stream>>>(
            xq, wtc[l], nullptr, hs, as_s, conv_as + (size_t)(l * 5) * HID, NQ);
        if (l == 0)
            gat_span_k<false><<<dim3(((size_t)NS * 64 + 255) / 256), dim3(256), 0, stream>>>(
                row_ptr, col, as_s, hs, xs, wd2 + 0 * HID, conv_b + (size_t)0 * HID,
                nullptr, nullptr, nullptr, NS);
        else
            gat_span_k<true><<<dim3(((size_t)NS * 64 + 255) / 256), dim3(256), 0, stream>>>(
                row_ptr, col, as_s, hs, xs, wd2 + 1 * HID, conv_b + (size_t)(5) * HID,
                out_W, out_b, (float*)d_out, NS);
    }
}

// Round 6
// 137.167 us; speedup vs baseline: 15.2383x; 1.4802x over previous
//
#include <hip/hip_runtime.h>

#define IN_DIM 256
#define HID 128

using bf16x8 = __attribute__((ext_vector_type(8))) short;
using f32x4 = __attribute__((ext_vector_type(4))) float;

__device__ __forceinline__ unsigned short f2bf(float f) {
    unsigned u = __float_as_uint(f);
    u += 0x7fffu + ((u >> 16) & 1u);  // RNE (inputs finite)
    return (unsigned short)(u >> 16);
}

// ---------- weight transpose+convert: W[K][128] fp32 -> Wt[K/8][128][8] bf16 ----------
__global__ __launch_bounds__(256) void wtcvt_k(const float* __restrict__ W,
                                               short* __restrict__ Wt, int total) {
    const int idx = blockIdx.x * blockDim.x + threadIdx.x;
    if (idx >= total) return;
    const int kkblk = idx >> 10;
    const int n = (idx >> 3) & 127;
    const int t = idx & 7;
    const int k = (kkblk << 3) | t;
    Wt[idx] = (short)f2bf(W[(size_t)k * HID + n]);
}

// ---------- MFMA GEMM (single weight): C[N,128] = A[N,K] @ Wt (+bias) ----------
template <int K>
__global__ __launch_bounds__(256) void gemm_mfma(const float* __restrict__ A,
                                                 const short* __restrict__ Wt,
                                                 const float* __restrict__ bias,
                                                 float* __restrict__ C, int N) {
    const int tid = threadIdx.x;
    const int w = tid >> 6;
    const int lane = tid & 63;
    const int m16 = lane & 15;
    const int kg = lane >> 4;

    const int arow = blockIdx.x * 64 + w * 16 + m16;
    const bool ok = arow < N;

    f32x4 acc[8];
#pragma unroll
    for (int j = 0; j < 8; ++j) acc[j] = (f32x4){0.f, 0.f, 0.f, 0.f};

    for (int k0 = 0; k0 < K; k0 += 32) {
        bf16x8 af = {0, 0, 0, 0, 0, 0, 0, 0};
        if (ok) {
            const float* ap = A + (size_t)arow * K + k0 + kg * 8;
            const float4 f0 = *reinterpret_cast<const float4*>(ap);
            const float4 f1 = *reinterpret_cast<const float4*>(ap + 4);
            af[0] = (short)f2bf(f0.x); af[1] = (short)f2bf(f0.y);
            af[2] = (short)f2bf(f0.z); af[3] = (short)f2bf(f0.w);
            af[4] = (short)f2bf(f1.x); af[5] = (short)f2bf(f1.y);
            af[6] = (short)f2bf(f1.z); af[7] = (short)f2bf(f1.w);
        }
        const short* bbase = Wt + (((k0 >> 3) + kg) << 10);
#pragma unroll
        for (int j = 0; j < 8; ++j) {
            const bf16x8 bf = *reinterpret_cast<const bf16x8*>(bbase + ((j * 16 + m16) << 3));
            acc[j] = __builtin_amdgcn_mfma_f32_16x16x32_bf16(af, bf, acc[j], 0, 0, 0);
        }
    }

    const int rbase = blockIdx.x * 64 + w * 16 + kg * 4;
    float bj[8];
#pragma unroll
    for (int j = 0; j < 8; ++j) bj[j] = bias ? bias[j * 16 + m16] : 0.f;
#pragma unroll
    for (int j = 0; j < 8; ++j)
#pragma unroll
        for (int r = 0; r < 4; ++r) {
            const int row = rbase + r;
            if (row < N) C[(size_t)row * HID + j * 16 + m16] = acc[j][r] + bj[j];
        }
}

// ---------- dual MFMA GEMM: hs[N][256] = A[N,128] @ {Wt0|Wt1}, fused as1/as2 ----------
__global__ __launch_bounds__(256) void gemm_dual_k(const float* __restrict__ A,
                                                   const short* __restrict__ Wt0,
                                                   const short* __restrict__ Wt1,
                                                   float* __restrict__ C,
                                                   float* __restrict__ as1,
                                                   float* __restrict__ as2,
                                                   const float* __restrict__ a1v,
                                                   const float* __restrict__ a2v, int N) {
    const int tid = threadIdx.x;
    const int w = tid >> 6;
    const int lane = tid & 63;
    const int m16 = lane & 15;
    const int kg = lane >> 4;

    const int arow = blockIdx.x * 64 + w * 16 + m16;
    const bool ok = arow < N;

    f32x4 acc[16];
#pragma unroll
    for (int j = 0; j < 16; ++j) acc[j] = (f32x4){0.f, 0.f, 0.f, 0.f};

    for (int k0 = 0; k0 < HID; k0 += 32) {
        bf16x8 af = {0, 0, 0, 0, 0, 0, 0, 0};
        if (ok) {
            const float* ap = A + (size_t)arow * HID + k0 + kg * 8;
            const float4 f0 = *reinterpret_cast<const float4*>(ap);
            const float4 f1 = *reinterpret_cast<const float4*>(ap + 4);
            af[0] = (short)f2bf(f0.x); af[1] = (short)f2bf(f0.y);
            af[2] = (short)f2bf(f0.z); af[3] = (short)f2bf(f0.w);
            af[4] = (short)f2bf(f1.x); af[5] = (short)f2bf(f1.y);
            af[6] = (short)f2bf(f1.z); af[7] = (short)f2bf(f1.w);
        }
        const int boff = ((k0 >> 3) + kg) << 10;
        const short* b0 = Wt0 + boff;
        const short* b1 = Wt1 + boff;
#pragma unroll
        for (int j = 0; j < 8; ++j) {
            const bf16x8 bf0 = *reinterpret_cast<const bf16x8*>(b0 + ((j * 16 + m16) << 3));
            acc[j] = __builtin_amdgcn_mfma_f32_16x16x32_bf16(af, bf0, acc[j], 0, 0, 0);
            const bf16x8 bf1 = *reinterpret_cast<const bf16x8*>(b1 + ((j * 16 + m16) << 3));
            acc[j + 8] = __builtin_amdgcn_mfma_f32_16x16x32_bf16(af, bf1, acc[j + 8], 0, 0, 0);
        }
    }

    const int rbase = blockIdx.x * 64 + w * 16 + kg * 4;
#pragma unroll
    for (int j = 0; j < 16; ++j)
#pragma unroll
        for (int r = 0; r < 4; ++r) {
            const int row = rbase + r;
            if (row < N) C[(size_t)row * 256 + j * 16 + m16] = acc[j][r];
        }

    float p1[4] = {0.f, 0.f, 0.f, 0.f};
    float p2[4] = {0.f, 0.f, 0.f, 0.f};
#pragma unroll
    for (int j = 0; j < 8; ++j) {
        const float a1 = a1v[j * 16 + m16];
        const float a2 = a2v[j * 16 + m16];
#pragma unroll
        for (int r = 0; r < 4; ++r) {
            p1[r] += acc[j][r] * a1;
            p2[r] += acc[j + 8][r] * a2;
        }
    }
#pragma unroll
    for (int off = 8; off > 0; off >>= 1)
#pragma unroll
        for (int r = 0; r < 4; ++r) {
            p1[r] += __shfl_xor(p1[r], off, 64);
            p2[r] += __shfl_xor(p2[r], off, 64);
        }
    if (m16 == 0)
#pragma unroll
        for (int r = 0; r < 4; ++r) {
            const int row = rbase + r;
            if (row < N) {
                as1[row] = p1[r];
                as2[row] = p2[r];
            }
        }
}

// ---------- wd[l*128+j] = dot(conv_Wd[l,0,j,:], conv_ad[l,0,:]) ----------
__global__ __launch_bounds__(256) void wd2_k(const float* __restrict__ Wd,
                                             const float* __restrict__ ad,
                                             float* __restrict__ wd_out) {
    const int idx = blockIdx.x * blockDim.x + threadIdx.x;
    const int row = idx >> 6;
    const int lane = threadIdx.x & 63;
    if (row >= 2 * HID) return;
    const int l = row >> 7;
    const int j = row & 127;
    const float* w = Wd + ((size_t)(l * 5) * HID + j) * HID;
    const float* a = ad + (size_t)(l * 5) * HID;
    float p = w[lane] * a[lane] + w[lane + 64] * a[lane + 64];
#pragma unroll
    for (int off = 32; off > 0; off >>= 1) p += __shfl_xor(p, off, 64);
    if (lane == 0) wd_out[row] = p;
}

// ---------- v2[k] = dot(lin_W[2][k][:], wd1); c2 = dot(lin_b[2], wd1) ----------
__global__ __launch_bounds__(256) void v2c2_k(const float* __restrict__ lin_W,
                                              const float* __restrict__ lin_b,
                                              const float* __restrict__ wd1,
                                              float* __restrict__ v2,
                                              float* __restrict__ c2) {
    const int idx = blockIdx.x * blockDim.x + threadIdx.x;
    const int row = idx >> 6;
    const int lane = threadIdx.x & 63;
    if (row > IN_DIM) return;
    const float* w = (row < IN_DIM) ? (lin_W + 2 * (size_t)IN_DIM * HID + (size_t)row * HID)
                                    : (lin_b + 2 * HID);
    float p = w[lane] * wd1[lane] + w[lane + 64] * wd1[lane + 64];
#pragma unroll
    for (int off = 32; off > 0; off >>= 1) p += __shfl_xor(p, off, 64);
    if (lane == 0) {
        if (row < IN_DIM) v2[row] = p;
        else c2[0] = p;
    }
}

// ---------- ad1[row] = dot(x_span[row,:256], v2) + c2 (wave per row) ----------
__global__ __launch_bounds__(256) void ad1_k(const float* __restrict__ X,
                                             const float* __restrict__ v2,
                                             const float* __restrict__ c2,
                                             float* __restrict__ ad1, int N) {
    const int idx = blockIdx.x * blockDim.x + threadIdx.x;
    const int row = idx >> 6;
    const int lane = threadIdx.x & 63;
    if (row >= N) return;
    const float4 x = *reinterpret_cast<const float4*>(X + (size_t)row * IN_DIM + lane * 4);
    const float4 v = *reinterpret_cast<const float4*>(v2 + lane * 4);
    float p = x.x * v.x + x.y * v.y + x.z * v.z + x.w * v.w;
#pragma unroll
    for (int off = 32; off > 0; off >>= 1) p += __shfl_xor(p, off, 64);
    if (lane == 0) ad1[row] = p + c2[0];
}

// ================= CSR build for the single live relation ==========
__global__ __launch_bounds__(256) void hist_k(const int* __restrict__ dst,
                                              int* __restrict__ deg, int E) {
    const int e = blockIdx.x * blockDim.x + threadIdx.x;
    if (e < E) atomicAdd(deg + dst[e], 1);
}

__global__ __launch_bounds__(256) void scan_partial_k(const int* __restrict__ deg,
                                                      int* __restrict__ partial, int total) {
    const int tid = threadIdx.x;
    const int base = blockIdx.x * 1024 + tid * 4;
    int s = 0;
#pragma unroll
    for (int i = 0; i < 4; ++i) {
        const int idx = base + i;
        if (idx < total) s += deg[idx];
    }
    __shared__ int red[4];
    int w = s;
#pragma unroll
    for (int off = 32; off > 0; off >>= 1) w += __shfl_xor(w, off, 64);
    if ((tid & 63) == 0) red[tid >> 6] = w;
    __syncthreads();
    if (tid == 0) partial[blockIdx.x] = red[0] + red[1] + red[2] + red[3];
}

__global__ __launch_bounds__(256) void scan_partials_k(int* __restrict__ partial, int nb) {
    __shared__ int sc[256];
    const int tid = threadIdx.x;
    const int v = (tid < nb) ? partial[tid] : 0;
    sc[tid] = v;
    __syncthreads();
    for (int off = 1; off < 256; off <<= 1) {
        const int u = (tid >= off) ? sc[tid - off] : 0;
        __syncthreads();
        sc[tid] += u;
        __syncthreads();
    }
    if (tid < nb) partial[tid] = sc[tid] - v;  // exclusive
}

__global__ __launch_bounds__(256) void scan_write_k(const int* __restrict__ deg,
                                                    const int* __restrict__ partial,
                                                    int* __restrict__ row_ptr,
                                                    int* __restrict__ cursor, int total,
                                                    int grand_total) {
    const int tid = threadIdx.x;
    const int base = blockIdx.x * 1024 + tid * 4;
    int v[4];
    int s = 0;
#pragma unroll
    for (int i = 0; i < 4; ++i) {
        const int idx = base + i;
        v[i] = (idx < total) ? deg[idx] : 0;
        s += v[i];
    }
    __shared__ int sc[256];
    sc[tid] = s;
    __syncthreads();
    for (int off = 1; off < 256; off <<= 1) {
        const int u = (tid >= off) ? sc[tid - off] : 0;
        __syncthreads();
        sc[tid] += u;
        __syncthreads();
    }
    int run = partial[blockIdx.x] + sc[tid] - s;
#pragma unroll
    for (int i = 0; i < 4; ++i) {
        const int idx = base + i;
        if (idx < total) {
            row_ptr[idx] = run;
            cursor[idx] = run;
            run += v[i];
        }
    }
    if (blockIdx.x == 0 && tid == 0) row_ptr[total] = grand_total;
}

__global__ __launch_bounds__(256) void scatter_k(const int* __restrict__ src,
                                                 const int* __restrict__ dst,
                                                 int* __restrict__ cursor,
                                                 int* __restrict__ col, int E) {
    const int e = blockIdx.x * blockDim.x + threadIdx.x;
    if (e >= E) return;
    const int pos = atomicAdd(cursor + dst[e], 1);
    col[pos] = src[e];
}

// ========== fused GAT, 16 lanes per dst row (4 rows/wave) ==========
// out[row] = dot(relu(softmax-gather + bias), dvec) + dbias
__global__ __launch_bounds__(256) void gat16_k(const int* __restrict__ row_ptr,
                                               const int* __restrict__ col,
                                               const float* __restrict__ as_s,
                                               const float* __restrict__ ad_s,
                                               const float* __restrict__ hs, int hoff,
                                               const float* __restrict__ bias,
                                               const float* __restrict__ dvec,
                                               const float* __restrict__ dbias,
                                               float* __restrict__ outv, int Ndst) {
    const int gidx = blockIdx.x * blockDim.x + threadIdx.x;
    const int row = gidx >> 4;
    const int sl = threadIdx.x & 15;
    if (row >= Ndst) return;
    const float ad = ad_s[row];
    const int beg = row_ptr[row];
    const int end = row_ptr[row + 1];

    // online max + denom (16 edges per batch, usually 1 batch)
    float m = -INFINITY, dsum = 0.f;
    for (int base = beg; base < end; base += 16) {
        const int e = base + sl;
        float ev = -INFINITY;
        if (e < end) {
            const float t = as_s[col[e]] + ad;
            ev = t > 0.f ? t : 0.2f * t;
        }
        float gm = ev;
#pragma unroll
        for (int off = 8; off > 0; off >>= 1) gm = fmaxf(gm, __shfl_xor(gm, off, 64));
        float ex = (e < end) ? expf(ev - gm) : 0.f;
#pragma unroll
        for (int off = 8; off > 0; off >>= 1) ex += __shfl_xor(ex, off, 64);
        dsum = dsum * expf(m - gm) + ex;
        m = gm;
    }
    const float inv = 1.f / (dsum + 1e-16f);

    // serial gather: group reads 512B row (32B/lane)
    f32x4 acc0 = {0.f, 0.f, 0.f, 0.f}, acc1 = {0.f, 0.f, 0.f, 0.f};
    for (int e = beg; e < end; ++e) {
        const int s = col[e];
        float t = as_s[s] + ad;
        t = t > 0.f ? t : 0.2f * t;
        const float alpha = expf(t - m) * inv;
        const float* h = hs + (size_t)s * 256 + hoff + sl * 8;
        const f32x4 h0 = *reinterpret_cast<const f32x4*>(h);
        const f32x4 h1 = *reinterpret_cast<const f32x4*>(h + 4);
#pragma unroll
        for (int i = 0; i < 4; ++i) {
            acc0[i] += alpha * h0[i];
            acc1[i] += alpha * h1[i];
        }
    }

    // epilogue: relu(acc+bias) · dvec
    const f32x4 b0 = *reinterpret_cast<const f32x4*>(bias + sl * 8);
    const f32x4 b1 = *reinterpret_cast<const f32x4*>(bias + sl * 8 + 4);
    const f32x4 d0 = *reinterpret_cast<const f32x4*>(dvec + sl * 8);
    const f32x4 d1 = *reinterpret_cast<const f32x4*>(dvec + sl * 8 + 4);
    float p = 0.f;
#pragma unroll
    for (int i = 0; i < 4; ++i) {
        p += fmaxf(acc0[i] + b0[i], 0.f) * d0[i];
        p += fmaxf(acc1[i] + b1[i], 0.f) * d1[i];
    }
#pragma unroll
    for (int off = 8; off > 0; off >>= 1) p += __shfl_xor(p, off, 64);
    if (sl == 0) outv[row] = p + (dbias ? dbias[0] : 0.f);
}

extern "C" void kernel_launch(void* const* d_in, const int* in_sizes, int n_in,
                              void* d_out, int out_size, void* d_ws, size_t ws_size,
                              hipStream_t stream) {
    // Live dataflow: out = relu(gat2)·outW; gat2 needs {hs2,as2} (from xq), ad2;
    // ad2 = relu(gat1+b1)·wd2; gat1 needs {hs1,as1}, ad1 = x_span@(linW2·wd1)+linb2·wd1.
    const float* x_qent = (const float*)d_in[0];
    const float* x_span = (const float*)d_in[2];
    const int* e_qs = (const int*)d_in[4];  // [2][E]
    const float* lin_W = (const float*)d_in[9];
    const float* lin_b = (const float*)d_in[10];
    const float* conv_Ws = (const float*)d_in[11];
    const float* conv_Wd = (const float*)d_in[12];
    const float* conv_as = (const float*)d_in[13];
    const float* conv_ad = (const float*)d_in[14];
    const float* conv_b = (const float*)d_in[15];
    const float* out_W = (const float*)d_in[16];
    const float* out_b = (const float*)d_in[17];

    const int NQ = in_sizes[0] / IN_DIM;
    const int NS = in_sizes[2] / IN_DIM;
    const int E = in_sizes[4] / 2;
    const int* srcp = e_qs;
    const int* dstp = e_qs + E;
    (void)n_in; (void)out_size;

    // ---- workspace carve ----
    float* ws = (float*)d_ws;
    size_t off = 0;
    auto alloc = [&](size_t n) { float* p = ws + off; off += n; return p; };
    float* xq = alloc((size_t)NQ * HID);
    float* hs = alloc((size_t)NQ * 256);  // [NQ][256]: cols 0:128 layer1, 128:256 layer2
    float* as1 = alloc(NQ);
    float* as2 = alloc(NQ);
    float* ad1 = alloc(NS);
    float* ad2 = alloc(NS);
    float* wd2 = alloc(2 * HID);
    float* v2 = alloc(IN_DIM);
    float* c2 = alloc(1);
    int* deg = (int*)alloc(NS);
    int* cursor = (int*)alloc(NS);
    int* row_ptr = (int*)alloc((size_t)NS + 1);
    int* partial = (int*)alloc(256);
    int* col = (int*)alloc(E);
    short* wt_lin0 = (short*)alloc(IN_DIM * HID / 2);
    short* wt_conv0 = (short*)alloc(HID * HID / 2);
    short* wt_conv5 = (short*)alloc(HID * HID / 2);
    (void)ws_size;

    // 0a. weight transpose+convert (live slices only)
    wtcvt_k<<<dim3((IN_DIM * HID + 255) / 256), dim3(256), 0, stream>>>(
        lin_W, wt_lin0, IN_DIM * HID);
    wtcvt_k<<<dim3((HID * HID + 255) / 256), dim3(256), 0, stream>>>(
        conv_Ws, wt_conv0, HID * HID);
    wtcvt_k<<<dim3((HID * HID + 255) / 256), dim3(256), 0, stream>>>(
        conv_Ws + 5 * (size_t)HID * HID, wt_conv5, HID * HID);

    // 0b. wd vectors, then collapsed SPAN-projection vector v2/c2
    wd2_k<<<dim3((2 * HID * 64 + 255) / 256), dim3(256), 0, stream>>>(conv_Wd, conv_ad, wd2);
    v2c2_k<<<dim3(((IN_DIM + 1) * 64 + 255) / 256), dim3(256), 0, stream>>>(
        lin_W, lin_b, wd2, v2, c2);

    // 0c. dst-CSR for r0
    const int nb = (NS + 1023) / 1024;
    hipMemsetAsync(deg, 0, (size_t)NS * 4, stream);
    hist_k<<<dim3((E + 255) / 256), dim3(256), 0, stream>>>(dstp, deg, E);
    scan_partial_k<<<dim3(nb), dim3(256), 0, stream>>>(deg, partial, NS);
    scan_partials_k<<<dim3(1), dim3(256), 0, stream>>>(partial, nb);
    scan_write_k<<<dim3(nb), dim3(256), 0, stream>>>(deg, partial, row_ptr, cursor, NS, E);
    scatter_k<<<dim3((E + 255) / 256), dim3(256), 0, stream>>>(srcp, dstp, cursor, col, E);

    // 1. QENT projection; ad1 matvec over raw x_span
    gemm_mfma<IN_DIM><<<dim3((NQ + 63) / 64), dim3(256), 0, stream>>>(
        x_qent, wt_lin0, lin_b, xq, NQ);
    ad1_k<<<dim3(((size_t)NS * 64 + 255) / 256), dim3(256), 0, stream>>>(
        x_span, v2, c2, ad1, NS);

    // 2. both layers' hs + fused as1/as2 in one GEMM
    gemm_dual_k<<<dim3((NQ + 63) / 64), dim3(256), 0, stream>>>(
        xq, wt_conv0, wt_conv5, hs, as1, as2, conv_as, conv_as + 5 * (size_t)HID, NQ);

    // 3. layer-1 GAT -> ad2 only; layer-2 GAT -> final output
    gat16_k<<<dim3(((size_t)NS * 16 + 255) / 256), dim3(256), 0, stream>>>(
        row_ptr, col, as1, ad1, hs, 0, conv_b, wd2 + HID, nullptr, ad2, NS);
    gat16_k<<<dim3(((size_t)NS * 16 + 255) / 256), dim3(256), 0, stream>>>(
        row_ptr, col, as2, ad2, hs, HID, conv_b + 5 * (size_t)HID, out_W, out_b,
        (float*)d_out, NS);
}